// Round 2
// baseline (19117.232 us; speedup 1.0000x reference)
//
#include <hip/hip_runtime.h>

#define NHID 128
#define NHEAD 8
#define NDIM 16
#define NNODE 100000
#define NEDGE 500000
#define NEG 0.2f

typedef float4 f4;

// C[N][128] = A[N][128] @ W[128][128] + bias
__global__ __launch_bounds__(256) void gemm128_bias(
    const float* __restrict__ A, const float* __restrict__ W,
    const float* __restrict__ bias, float* __restrict__ C, int N)
{
    __shared__ __align__(16) float Wl[128][132];
    __shared__ __align__(16) float Xl[128][17];
    const int tid = threadIdx.x;
    const int row0 = blockIdx.x * 128;
    for (int i = tid; i < 4096; i += 256) {
        int k = i >> 5, c = (i & 31) << 2;
        f4 w = reinterpret_cast<const f4*>(W)[i];
        Wl[k][c] = w.x; Wl[k][c+1] = w.y; Wl[k][c+2] = w.z; Wl[k][c+3] = w.w;
    }
    const int tr = tid >> 4, tc = tid & 15;
    float acc[8][8];
    #pragma unroll
    for (int i = 0; i < 8; ++i)
        #pragma unroll
        for (int j = 0; j < 8; ++j) acc[i][j] = 0.f;

    for (int k0 = 0; k0 < 128; k0 += 16) {
        __syncthreads();
        for (int i = tid; i < 512; i += 256) {
            int r = i >> 2, q = i & 3;
            int gr = row0 + r;
            f4 v = make_float4(0.f, 0.f, 0.f, 0.f);
            if (gr < N) v = reinterpret_cast<const f4*>(A + (size_t)gr * 128 + k0)[q];
            int c = q << 2;
            Xl[r][c] = v.x; Xl[r][c+1] = v.y; Xl[r][c+2] = v.z; Xl[r][c+3] = v.w;
        }
        __syncthreads();
        #pragma unroll
        for (int kk = 0; kk < 16; ++kk) {
            float xv[8], wv[8];
            #pragma unroll
            for (int i = 0; i < 8; ++i) xv[i] = Xl[tr * 8 + i][kk];
            f4 w0 = *reinterpret_cast<const f4*>(&Wl[k0 + kk][tc * 8]);
            f4 w1 = *reinterpret_cast<const f4*>(&Wl[k0 + kk][tc * 8 + 4]);
            wv[0]=w0.x; wv[1]=w0.y; wv[2]=w0.z; wv[3]=w0.w;
            wv[4]=w1.x; wv[5]=w1.y; wv[6]=w1.z; wv[7]=w1.w;
            #pragma unroll
            for (int i = 0; i < 8; ++i)
                #pragma unroll
                for (int j = 0; j < 8; ++j) acc[i][j] = fmaf(xv[i], wv[j], acc[i][j]);
        }
    }
    float bv[8];
    #pragma unroll
    for (int j = 0; j < 8; ++j) bv[j] = bias[tc * 8 + j];
    #pragma unroll
    for (int i = 0; i < 8; ++i) {
        int gr = row0 + tr * 8 + i;
        if (gr < N) {
            f4 o0 = make_float4(acc[i][0]+bv[0], acc[i][1]+bv[1], acc[i][2]+bv[2], acc[i][3]+bv[3]);
            f4 o1 = make_float4(acc[i][4]+bv[4], acc[i][5]+bv[5], acc[i][6]+bv[6], acc[i][7]+bv[7]);
            f4* cp = reinterpret_cast<f4*>(C + (size_t)gr * 128 + tc * 8);
            cp[0] = o0; cp[1] = o1;
        }
    }
}

// macc[c] += sum over rows of tanh(A@W + bias)[c]
__global__ __launch_bounds__(256) void score_reduce(
    const float* __restrict__ A, const float* __restrict__ W,
    const float* __restrict__ bias, float* __restrict__ macc, int N)
{
    __shared__ __align__(16) float Wl[128][132];
    __shared__ __align__(16) float Xl[128][17];
    const int tid = threadIdx.x;
    const int row0 = blockIdx.x * 128;
    for (int i = tid; i < 4096; i += 256) {
        int k = i >> 5, c = (i & 31) << 2;
        f4 w = reinterpret_cast<const f4*>(W)[i];
        Wl[k][c] = w.x; Wl[k][c+1] = w.y; Wl[k][c+2] = w.z; Wl[k][c+3] = w.w;
    }
    const int tr = tid >> 4, tc = tid & 15;
    float acc[8][8];
    #pragma unroll
    for (int i = 0; i < 8; ++i)
        #pragma unroll
        for (int j = 0; j < 8; ++j) acc[i][j] = 0.f;

    for (int k0 = 0; k0 < 128; k0 += 16) {
        __syncthreads();
        for (int i = tid; i < 512; i += 256) {
            int r = i >> 2, q = i & 3;
            int gr = row0 + r;
            f4 v = make_float4(0.f, 0.f, 0.f, 0.f);
            if (gr < N) v = reinterpret_cast<const f4*>(A + (size_t)gr * 128 + k0)[q];
            int c = q << 2;
            Xl[r][c] = v.x; Xl[r][c+1] = v.y; Xl[r][c+2] = v.z; Xl[r][c+3] = v.w;
        }
        __syncthreads();
        #pragma unroll
        for (int kk = 0; kk < 16; ++kk) {
            float xv[8], wv[8];
            #pragma unroll
            for (int i = 0; i < 8; ++i) xv[i] = Xl[tr * 8 + i][kk];
            f4 w0 = *reinterpret_cast<const f4*>(&Wl[k0 + kk][tc * 8]);
            f4 w1 = *reinterpret_cast<const f4*>(&Wl[k0 + kk][tc * 8 + 4]);
            wv[0]=w0.x; wv[1]=w0.y; wv[2]=w0.z; wv[3]=w0.w;
            wv[4]=w1.x; wv[5]=w1.y; wv[6]=w1.z; wv[7]=w1.w;
            #pragma unroll
            for (int i = 0; i < 8; ++i)
                #pragma unroll
                for (int j = 0; j < 8; ++j) acc[i][j] = fmaf(xv[i], wv[j], acc[i][j]);
        }
    }
    float bv[8];
    #pragma unroll
    for (int j = 0; j < 8; ++j) bv[j] = bias[tc * 8 + j];
    float colsum[8];
    #pragma unroll
    for (int j = 0; j < 8; ++j) colsum[j] = 0.f;
    #pragma unroll
    for (int i = 0; i < 8; ++i) {
        int gr = row0 + tr * 8 + i;
        if (gr < N) {
            #pragma unroll
            for (int j = 0; j < 8; ++j) colsum[j] += tanhf(acc[i][j] + bv[j]);
        }
    }
    __syncthreads();
    float* flat = &Xl[0][0];
    #pragma unroll
    for (int j = 0; j < 8; ++j) flat[tr * 128 + tc * 8 + j] = colsum[j];
    __syncthreads();
    if (tid < 128) {
        float s = 0.f;
        #pragma unroll
        for (int t = 0; t < 16; ++t) s += flat[t * 128 + tid];
        atomicAdd(macc + tid, s);
    }
}

// out[n*8+h] = dot(z[n, h*16:(h+1)*16], av[h*16:(h+1)*16])
__global__ __launch_bounds__(256) void node_alpha(
    const float* __restrict__ z, const float* __restrict__ av,
    float* __restrict__ out, int N)
{
    int idx = blockIdx.x * 256 + threadIdx.x;
    if (idx >= N * 8) return;
    int n = idx >> 3, h = idx & 7;
    const f4* zp = reinterpret_cast<const f4*>(z + (size_t)n * 128 + h * 16);
    const f4* ap = reinterpret_cast<const f4*>(av + h * 16);
    float s = 0.f;
    #pragma unroll
    for (int i = 0; i < 4; ++i) {
        f4 a = zp[i], b = ap[i];
        s += a.x*b.x + a.y*b.y + a.z*b.z + a.w*b.w;
    }
    out[idx] = s;
}

// one thread per (edge, head): p = exp(leakyrelu(asrc+adst)); scatter p and p*z
__global__ __launch_bounds__(256) void edge_pass(
    const int* __restrict__ ei, const float* __restrict__ asrc,
    const float* __restrict__ adst, const float* __restrict__ zsrc,
    float* __restrict__ ssum, float* __restrict__ outacc)
{
    int idx = blockIdx.x * 256 + threadIdx.x;
    if (idx >= NEDGE * 8) return;
    int e = idx >> 3, h = idx & 7;
    int s = ei[e], d = ei[NEDGE + e];
    float a = asrc[s * 8 + h] + adst[d * 8 + h];
    a = (a >= 0.f) ? a : NEG * a;
    float p = expf(a);
    atomicAdd(ssum + d * 8 + h, p);
    const f4* zr = reinterpret_cast<const f4*>(zsrc + (size_t)s * 128 + h * 16);
    float* orow = outacc + (size_t)d * 128 + h * 16;
    #pragma unroll
    for (int q = 0; q < 4; ++q) {
        f4 z = zr[q];
        atomicAdd(orow + q * 4 + 0, p * z.x);
        atomicAdd(orow + q * 4 + 1, p * z.y);
        atomicAdd(orow + q * 4 + 2, p * z.z);
        atomicAdd(orow + q * 4 + 3, p * z.w);
    }
}

// out = relu(out / (ssum + 1e-16)), vectorized 4 floats (same head per float4)
__global__ __launch_bounds__(256) void finalize_seg(
    float* __restrict__ out, const float* __restrict__ ssum, int n4)
{
    int i = blockIdx.x * 256 + threadIdx.x;
    if (i >= n4) return;
    int f0 = i * 4;
    int n = f0 >> 7;
    int h = (f0 >> 4) & 7;
    float inv = 1.0f / (ssum[n * 8 + h] + 1e-16f);
    f4 v = reinterpret_cast<f4*>(out)[i];
    v.x = fmaxf(v.x * inv, 0.f);
    v.y = fmaxf(v.y * inv, 0.f);
    v.z = fmaxf(v.z * inv, 0.f);
    v.w = fmaxf(v.w * inv, 0.f);
    reinterpret_cast<f4*>(out)[i] = v;
}

// softmax over the two semantic scores
__global__ void attn_small(const float* __restrict__ macc,
                           const float* __restrict__ qv, float* __restrict__ attn)
{
    __shared__ float s0[128], s1[128];
    int t = threadIdx.x;
    s0[t] = macc[t] * qv[t];
    s1[t] = macc[128 + t] * qv[t];
    __syncthreads();
    if (t == 0) {
        float a = 0.f, b = 0.f;
        for (int i = 0; i < 128; ++i) { a += s0[i]; b += s1[i]; }
        a *= (1.0f / 100000.0f);
        b *= (1.0f / 100000.0f);
        float m = fmaxf(a, b);
        float ea = expf(a - m), eb = expf(b - m);
        float inv = 1.f / (ea + eb);
        attn[0] = ea * inv;
        attn[1] = eb * inv;
    }
}

// dst = attn[0]*inA + attn[1]*inB  (dst may alias inA or inB)
__global__ __launch_bounds__(256) void combine2(
    float* __restrict__ dst, const float* __restrict__ inA,
    const float* __restrict__ inB, const float* __restrict__ attn, int n4)
{
    int i = blockIdx.x * 256 + threadIdx.x;
    if (i >= n4) return;
    float a0 = attn[0], a1 = attn[1];
    f4 A = reinterpret_cast<const f4*>(inA)[i];
    f4 B = reinterpret_cast<const f4*>(inB)[i];
    f4 r = make_float4(a0*A.x + a1*B.x, a0*A.y + a1*B.y,
                       a0*A.z + a1*B.z, a0*A.w + a1*B.w);
    reinterpret_cast<f4*>(dst)[i] = r;
}

// out[N][8] = X[N][128] @ W[128][8] + bias
__global__ __launch_bounds__(256) void final_gemm(
    const float* __restrict__ X, const float* __restrict__ W,
    const float* __restrict__ bias, float* __restrict__ out, int N)
{
    __shared__ float Ws[128][8];
    __shared__ __align__(16) float Xs[32][129];
    int tid = threadIdx.x;
    for (int i = tid; i < 1024; i += 256) Ws[i >> 3][i & 7] = W[i];
    int row0 = blockIdx.x * 32;
    for (int i = tid; i < 1024; i += 256) {
        int r = i >> 5, q = i & 31;
        int gr = row0 + r;
        f4 v = make_float4(0.f, 0.f, 0.f, 0.f);
        if (gr < N) v = reinterpret_cast<const f4*>(X + (size_t)gr * 128)[q];
        Xs[r][q*4] = v.x; Xs[r][q*4+1] = v.y; Xs[r][q*4+2] = v.z; Xs[r][q*4+3] = v.w;
    }
    __syncthreads();
    int r = tid >> 3, o = tid & 7;
    int gr = row0 + r;
    if (gr < N) {
        float s = bias[o];
        #pragma unroll
        for (int k = 0; k < 128; ++k) s = fmaf(Xs[r][k], Ws[k][o], s);
        out[(size_t)gr * 8 + o] = s;
    }
}

extern "C" void kernel_launch(void* const* d_in, const int* in_sizes, int n_in,
                              void* d_out, int out_size, void* d_ws, size_t ws_size,
                              hipStream_t stream) {
    const float* x_paper  = (const float*)d_in[0];
    const float* x_author = (const float*)d_in[1];
    const float* Wp_p = (const float*)d_in[2];
    const float* bp_p = (const float*)d_in[3];
    const float* Wp_a = (const float*)d_in[4];
    const float* bp_a = (const float*)d_in[5];
    const float* as_ap = (const float*)d_in[6];
    const float* ad_ap = (const float*)d_in[7];
    const float* as_pa = (const float*)d_in[8];
    const float* ad_pa = (const float*)d_in[9];
    const float* as_pp = (const float*)d_in[10];
    const float* ad_pp = (const float*)d_in[11];
    const float* Wk   = (const float*)d_in[12];
    const float* bk   = (const float*)d_in[13];
    const float* qv   = (const float*)d_in[14];
    const float* Wout = (const float*)d_in[15];
    const float* bout = (const float*)d_in[16];
    const int* ei_ap = (const int*)d_in[17];
    const int* ei_pa = (const int*)d_in[18];
    const int* ei_pp = (const int*)d_in[19];

    float* ws = (float*)d_ws;
    const size_t NB = (size_t)NNODE * 128;   // 12.8M floats
    float* B0 = ws;
    float* B1 = B0 + NB;
    float* B2 = B1 + NB;
    float* B3 = B2 + NB;
    float* p = B3 + NB;
    float* A0  = p; p += NNODE * 8;   // asrc (reused per edge type)
    float* A1  = p; p += NNODE * 8;   // adst (reused)
    float* SS  = p; p += NNODE * 8;   // ssum (reused)
    float* macc = p; p += 256;
    float* attn = p; p += 16;
    // total: 4*12.8M + 2.4M + 272 floats = 214.5 MB  (< 256 MiB)

    const dim3 blk(256);
    const int gemmGrid = (NNODE + 127) / 128;       // 782
    const int nodeGrid = (NNODE * 8) / 256;         // 3125
    const int edgeGrid = (NEDGE * 8) / 256;         // 15625
    const int vecGrid  = (NNODE * 128 / 4) / 256;   // 12500

    // One edge-type block: alpha projections -> clear -> scatter -> normalize.
    // zmsg doubles as the alpha_src feature source (z_src in the reference).
    auto run_edge = [&](const int* ei, const float* zmsg, const float* zdst,
                        const float* a_s, const float* a_d, float* out) {
        node_alpha<<<nodeGrid, blk, 0, stream>>>(zmsg, a_s, A0, NNODE);
        node_alpha<<<nodeGrid, blk, 0, stream>>>(zdst, a_d, A1, NNODE);
        hipMemsetAsync(SS, 0, (size_t)NNODE * 8 * 4, stream);
        hipMemsetAsync(out, 0, NB * 4, stream);
        edge_pass<<<edgeGrid, blk, 0, stream>>>(ei, A0, A1, zmsg, SS, out);
        finalize_seg<<<vecGrid, blk, 0, stream>>>(out, SS, NNODE * 32);
    };

    // ---------------- Layer 0 ----------------
    gemm128_bias<<<gemmGrid, blk, 0, stream>>>(x_paper,  Wp_p, bp_p, B0, NNODE);  // zp
    gemm128_bias<<<gemmGrid, blk, 0, stream>>>(x_author, Wp_a, bp_a, B1, NNODE);  // za

    run_edge(ei_ap, B1, B0, as_ap, ad_ap, B2);   // out_ap (author->paper)
    run_edge(ei_pa, B0, B1, as_pa, ad_pa, B3);   // out_pa = new_xa; za (B1) now dead
    run_edge(ei_pp, B0, B0, as_pp, ad_pp, B1);   // out_pp into B1; zp (B0) now dead

    hipMemsetAsync(macc, 0, 256 * 4, stream);
    score_reduce<<<gemmGrid, blk, 0, stream>>>(B2, Wk, bk, macc,       NNODE);
    score_reduce<<<gemmGrid, blk, 0, stream>>>(B1, Wk, bk, macc + 128, NNODE);
    attn_small<<<1, 128, 0, stream>>>(macc, qv, attn);
    combine2<<<vecGrid, blk, 0, stream>>>(B0, B2, B1, attn, NNODE * 32);  // new_xp -> B0

    // ---------------- Layer 1 ----------------  (pa edge type is dead code here)
    const int wo = 128 * 128, bo = 128, ao = 128;
    gemm128_bias<<<gemmGrid, blk, 0, stream>>>(B0, Wp_p + wo, bp_p + bo, B2, NNODE); // zp' -> B2
    gemm128_bias<<<gemmGrid, blk, 0, stream>>>(B3, Wp_a + wo, bp_a + bo, B1, NNODE); // za' -> B1

    run_edge(ei_ap, B1, B2, as_ap + ao, ad_ap + ao, B0);   // out_ap -> B0
    run_edge(ei_pp, B2, B2, as_pp + ao, ad_pp + ao, B3);   // out_pp -> B3

    hipMemsetAsync(macc, 0, 256 * 4, stream);
    score_reduce<<<gemmGrid, blk, 0, stream>>>(B0, Wk + wo, bk + bo, macc,       NNODE);
    score_reduce<<<gemmGrid, blk, 0, stream>>>(B3, Wk + wo, bk + bo, macc + 128, NNODE);
    attn_small<<<1, 128, 0, stream>>>(macc, qv + bo, attn);
    combine2<<<vecGrid, blk, 0, stream>>>(B1, B0, B3, attn, NNODE * 32);  // new_xp -> B1

    final_gemm<<<(NNODE + 31) / 32, blk, 0, stream>>>(B1, Wout, bout, (float*)d_out, NNODE);
}

// Round 3
// 1428.220 us; speedup vs baseline: 13.3854x; 13.3854x over previous
//
#include <hip/hip_runtime.h>

#define NHID 128
#define NHEAD 8
#define NDIM 16
#define NNODE 100000
#define NEDGE 500000
#define NEG 0.2f

typedef float4 f4;

// C[N][128] = A[N][128] @ W[128][128] + bias
__global__ __launch_bounds__(256) void gemm128_bias(
    const float* __restrict__ A, const float* __restrict__ W,
    const float* __restrict__ bias, float* __restrict__ C, int N)
{
    __shared__ __align__(16) float Wl[128][132];
    __shared__ __align__(16) float Xl[128][17];
    const int tid = threadIdx.x;
    const int row0 = blockIdx.x * 128;
    for (int i = tid; i < 4096; i += 256) {
        int k = i >> 5, c = (i & 31) << 2;
        f4 w = reinterpret_cast<const f4*>(W)[i];
        Wl[k][c] = w.x; Wl[k][c+1] = w.y; Wl[k][c+2] = w.z; Wl[k][c+3] = w.w;
    }
    const int tr = tid >> 4, tc = tid & 15;
    float acc[8][8];
    #pragma unroll
    for (int i = 0; i < 8; ++i)
        #pragma unroll
        for (int j = 0; j < 8; ++j) acc[i][j] = 0.f;

    for (int k0 = 0; k0 < 128; k0 += 16) {
        __syncthreads();
        for (int i = tid; i < 512; i += 256) {
            int r = i >> 2, q = i & 3;
            int gr = row0 + r;
            f4 v = make_float4(0.f, 0.f, 0.f, 0.f);
            if (gr < N) v = reinterpret_cast<const f4*>(A + (size_t)gr * 128 + k0)[q];
            int c = q << 2;
            Xl[r][c] = v.x; Xl[r][c+1] = v.y; Xl[r][c+2] = v.z; Xl[r][c+3] = v.w;
        }
        __syncthreads();
        #pragma unroll
        for (int kk = 0; kk < 16; ++kk) {
            float xv[8], wv[8];
            #pragma unroll
            for (int i = 0; i < 8; ++i) xv[i] = Xl[tr * 8 + i][kk];
            f4 w0 = *reinterpret_cast<const f4*>(&Wl[k0 + kk][tc * 8]);
            f4 w1 = *reinterpret_cast<const f4*>(&Wl[k0 + kk][tc * 8 + 4]);
            wv[0]=w0.x; wv[1]=w0.y; wv[2]=w0.z; wv[3]=w0.w;
            wv[4]=w1.x; wv[5]=w1.y; wv[6]=w1.z; wv[7]=w1.w;
            #pragma unroll
            for (int i = 0; i < 8; ++i)
                #pragma unroll
                for (int j = 0; j < 8; ++j) acc[i][j] = fmaf(xv[i], wv[j], acc[i][j]);
        }
    }
    float bv[8];
    #pragma unroll
    for (int j = 0; j < 8; ++j) bv[j] = bias[tc * 8 + j];
    #pragma unroll
    for (int i = 0; i < 8; ++i) {
        int gr = row0 + tr * 8 + i;
        if (gr < N) {
            f4 o0 = make_float4(acc[i][0]+bv[0], acc[i][1]+bv[1], acc[i][2]+bv[2], acc[i][3]+bv[3]);
            f4 o1 = make_float4(acc[i][4]+bv[4], acc[i][5]+bv[5], acc[i][6]+bv[6], acc[i][7]+bv[7]);
            f4* cp = reinterpret_cast<f4*>(C + (size_t)gr * 128 + tc * 8);
            cp[0] = o0; cp[1] = o1;
        }
    }
}

// macc[c] += sum over rows of tanh(A@W + bias)[c]
__global__ __launch_bounds__(256) void score_reduce(
    const float* __restrict__ A, const float* __restrict__ W,
    const float* __restrict__ bias, float* __restrict__ macc, int N)
{
    __shared__ __align__(16) float Wl[128][132];
    __shared__ __align__(16) float Xl[128][17];
    const int tid = threadIdx.x;
    const int row0 = blockIdx.x * 128;
    for (int i = tid; i < 4096; i += 256) {
        int k = i >> 5, c = (i & 31) << 2;
        f4 w = reinterpret_cast<const f4*>(W)[i];
        Wl[k][c] = w.x; Wl[k][c+1] = w.y; Wl[k][c+2] = w.z; Wl[k][c+3] = w.w;
    }
    const int tr = tid >> 4, tc = tid & 15;
    float acc[8][8];
    #pragma unroll
    for (int i = 0; i < 8; ++i)
        #pragma unroll
        for (int j = 0; j < 8; ++j) acc[i][j] = 0.f;

    for (int k0 = 0; k0 < 128; k0 += 16) {
        __syncthreads();
        for (int i = tid; i < 512; i += 256) {
            int r = i >> 2, q = i & 3;
            int gr = row0 + r;
            f4 v = make_float4(0.f, 0.f, 0.f, 0.f);
            if (gr < N) v = reinterpret_cast<const f4*>(A + (size_t)gr * 128 + k0)[q];
            int c = q << 2;
            Xl[r][c] = v.x; Xl[r][c+1] = v.y; Xl[r][c+2] = v.z; Xl[r][c+3] = v.w;
        }
        __syncthreads();
        #pragma unroll
        for (int kk = 0; kk < 16; ++kk) {
            float xv[8], wv[8];
            #pragma unroll
            for (int i = 0; i < 8; ++i) xv[i] = Xl[tr * 8 + i][kk];
            f4 w0 = *reinterpret_cast<const f4*>(&Wl[k0 + kk][tc * 8]);
            f4 w1 = *reinterpret_cast<const f4*>(&Wl[k0 + kk][tc * 8 + 4]);
            wv[0]=w0.x; wv[1]=w0.y; wv[2]=w0.z; wv[3]=w0.w;
            wv[4]=w1.x; wv[5]=w1.y; wv[6]=w1.z; wv[7]=w1.w;
            #pragma unroll
            for (int i = 0; i < 8; ++i)
                #pragma unroll
                for (int j = 0; j < 8; ++j) acc[i][j] = fmaf(xv[i], wv[j], acc[i][j]);
        }
    }
    float bv[8];
    #pragma unroll
    for (int j = 0; j < 8; ++j) bv[j] = bias[tc * 8 + j];
    float colsum[8];
    #pragma unroll
    for (int j = 0; j < 8; ++j) colsum[j] = 0.f;
    #pragma unroll
    for (int i = 0; i < 8; ++i) {
        int gr = row0 + tr * 8 + i;
        if (gr < N) {
            #pragma unroll
            for (int j = 0; j < 8; ++j) colsum[j] += tanhf(acc[i][j] + bv[j]);
        }
    }
    __syncthreads();
    float* flat = &Xl[0][0];
    #pragma unroll
    for (int j = 0; j < 8; ++j) flat[tr * 128 + tc * 8 + j] = colsum[j];
    __syncthreads();
    if (tid < 128) {
        float s = 0.f;
        #pragma unroll
        for (int t = 0; t < 16; ++t) s += flat[t * 128 + tid];
        atomicAdd(macc + tid, s);
    }
}

// out[n*8+h] = dot(z[n, h*16:(h+1)*16], av[h*16:(h+1)*16])
__global__ __launch_bounds__(256) void node_alpha(
    const float* __restrict__ z, const float* __restrict__ av,
    float* __restrict__ out, int N)
{
    int idx = blockIdx.x * 256 + threadIdx.x;
    if (idx >= N * 8) return;
    int n = idx >> 3, h = idx & 7;
    const f4* zp = reinterpret_cast<const f4*>(z + (size_t)n * 128 + h * 16);
    const f4* ap = reinterpret_cast<const f4*>(av + h * 16);
    float s = 0.f;
    #pragma unroll
    for (int i = 0; i < 4; ++i) {
        f4 a = zp[i], b = ap[i];
        s += a.x*b.x + a.y*b.y + a.z*b.z + a.w*b.w;
    }
    out[idx] = s;
}

// ---------------- CSR build ----------------
__global__ __launch_bounds__(256) void hist_dst(const int* __restrict__ ei, int* __restrict__ deg)
{
    int e = blockIdx.x * 256 + threadIdx.x;
    if (e < NEDGE) atomicAdd(deg + ei[NEDGE + e], 1);
}

__global__ __launch_bounds__(1024) void scan_block(const int* __restrict__ deg,
    int* __restrict__ offs, int* __restrict__ bsum, int N)
{
    __shared__ int sd[1024];
    int t = threadIdx.x, i = blockIdx.x * 1024 + t;
    int v = (i < N) ? deg[i] : 0;
    sd[t] = v; __syncthreads();
    for (int o = 1; o < 1024; o <<= 1) {
        int x = (t >= o) ? sd[t - o] : 0;
        __syncthreads();
        sd[t] += x;
        __syncthreads();
    }
    if (i < N) offs[i + 1] = sd[t];
    if (t == 1023) bsum[blockIdx.x] = sd[t];
}

__global__ void scan_bsum(const int* __restrict__ bsum, int* __restrict__ boff, int nb)
{
    if (threadIdx.x == 0) {
        int run = 0;
        for (int b = 0; b < nb; ++b) { boff[b] = run; run += bsum[b]; }
    }
}

__global__ __launch_bounds__(1024) void scan_add(int* __restrict__ offs,
    const int* __restrict__ boff, int N)
{
    int i = blockIdx.x * 1024 + threadIdx.x;
    if (i == 0) offs[0] = 0;
    if (i < N) offs[i + 1] += boff[blockIdx.x];
}

__global__ __launch_bounds__(256) void copy_int(const int* __restrict__ src,
    int* __restrict__ dst, int n)
{
    int i = blockIdx.x * 256 + threadIdx.x;
    if (i < n) dst[i] = src[i];
}

__global__ __launch_bounds__(256) void scatter_src(const int* __restrict__ ei,
    int* __restrict__ cursor, int* __restrict__ cols)
{
    int e = blockIdx.x * 256 + threadIdx.x;
    if (e < NEDGE) {
        int d = ei[NEDGE + e];
        int pos = atomicAdd(cursor + d, 1);
        cols[pos] = ei[e];
    }
}

// ---------------- gather aggregation ----------------
// one wave per dst node; lane owns dims (2*lane, 2*lane+1); head = lane>>3.
// out[d] = relu( sum_e p_e * z[src_e] / (sum_e p_e + 1e-16) ),
// p_e = exp(leakyrelu(asrc[src_e,h] + adst[d,h]))
__global__ __launch_bounds__(256) void agg_gather(
    const int* __restrict__ offs, const int* __restrict__ cols,
    const float* __restrict__ asrc, const float* __restrict__ adst,
    const float* __restrict__ z, float* __restrict__ out)
{
    int w = threadIdx.x >> 6;
    int lane = threadIdx.x & 63;
    int d = blockIdx.x * 4 + w;
    if (d >= NNODE) return;
    int h = lane >> 3;
    float ad = adst[d * 8 + h];
    int e0 = offs[d], e1 = offs[d + 1];
    float acc0 = 0.f, acc1 = 0.f, psum = 0.f;
    for (int e = e0; e < e1; ++e) {
        int s = cols[e];
        float a = asrc[s * 8 + h] + ad;
        a = (a >= 0.f) ? a : NEG * a;
        float p = __expf(a);
        float2 zv = *reinterpret_cast<const float2*>(z + (size_t)s * 128 + lane * 2);
        acc0 = fmaf(p, zv.x, acc0);
        acc1 = fmaf(p, zv.y, acc1);
        psum += p;
    }
    float inv = 1.f / (psum + 1e-16f);
    float2 o;
    o.x = fmaxf(acc0 * inv, 0.f);
    o.y = fmaxf(acc1 * inv, 0.f);
    *reinterpret_cast<float2*>(out + (size_t)d * 128 + lane * 2) = o;
}

// softmax over the two semantic scores
__global__ void attn_small(const float* __restrict__ macc,
                           const float* __restrict__ qv, float* __restrict__ attn)
{
    __shared__ float s0[128], s1[128];
    int t = threadIdx.x;
    s0[t] = macc[t] * qv[t];
    s1[t] = macc[128 + t] * qv[t];
    __syncthreads();
    if (t == 0) {
        float a = 0.f, b = 0.f;
        for (int i = 0; i < 128; ++i) { a += s0[i]; b += s1[i]; }
        a *= (1.0f / 100000.0f);
        b *= (1.0f / 100000.0f);
        float m = fmaxf(a, b);
        float ea = expf(a - m), eb = expf(b - m);
        float inv = 1.f / (ea + eb);
        attn[0] = ea * inv;
        attn[1] = eb * inv;
    }
}

// dst = attn[0]*inA + attn[1]*inB
__global__ __launch_bounds__(256) void combine2(
    float* __restrict__ dst, const float* __restrict__ inA,
    const float* __restrict__ inB, const float* __restrict__ attn, int n4)
{
    int i = blockIdx.x * 256 + threadIdx.x;
    if (i >= n4) return;
    float a0 = attn[0], a1 = attn[1];
    f4 A = reinterpret_cast<const f4*>(inA)[i];
    f4 B = reinterpret_cast<const f4*>(inB)[i];
    f4 r = make_float4(a0*A.x + a1*B.x, a0*A.y + a1*B.y,
                       a0*A.z + a1*B.z, a0*A.w + a1*B.w);
    reinterpret_cast<f4*>(dst)[i] = r;
}

// out[N][8] = X[N][128] @ W[128][8] + bias
__global__ __launch_bounds__(256) void final_gemm(
    const float* __restrict__ X, const float* __restrict__ W,
    const float* __restrict__ bias, float* __restrict__ out, int N)
{
    __shared__ float Ws[128][8];
    __shared__ __align__(16) float Xs[32][129];
    int tid = threadIdx.x;
    for (int i = tid; i < 1024; i += 256) Ws[i >> 3][i & 7] = W[i];
    int row0 = blockIdx.x * 32;
    for (int i = tid; i < 1024; i += 256) {
        int r = i >> 5, q = i & 31;
        int gr = row0 + r;
        f4 v = make_float4(0.f, 0.f, 0.f, 0.f);
        if (gr < N) v = reinterpret_cast<const f4*>(X + (size_t)gr * 128)[q];
        Xs[r][q*4] = v.x; Xs[r][q*4+1] = v.y; Xs[r][q*4+2] = v.z; Xs[r][q*4+3] = v.w;
    }
    __syncthreads();
    int r = tid >> 3, o = tid & 7;
    int gr = row0 + r;
    if (gr < N) {
        float s = bias[o];
        #pragma unroll
        for (int k = 0; k < 128; ++k) s = fmaf(Xs[r][k], Ws[k][o], s);
        out[(size_t)gr * 8 + o] = s;
    }
}

extern "C" void kernel_launch(void* const* d_in, const int* in_sizes, int n_in,
                              void* d_out, int out_size, void* d_ws, size_t ws_size,
                              hipStream_t stream) {
    const float* x_paper  = (const float*)d_in[0];
    const float* x_author = (const float*)d_in[1];
    const float* Wp_p = (const float*)d_in[2];
    const float* bp_p = (const float*)d_in[3];
    const float* Wp_a = (const float*)d_in[4];
    const float* bp_a = (const float*)d_in[5];
    const float* as_ap = (const float*)d_in[6];
    const float* ad_ap = (const float*)d_in[7];
    const float* as_pa = (const float*)d_in[8];
    const float* ad_pa = (const float*)d_in[9];
    const float* as_pp = (const float*)d_in[10];
    const float* ad_pp = (const float*)d_in[11];
    const float* Wk   = (const float*)d_in[12];
    const float* bk   = (const float*)d_in[13];
    const float* qv   = (const float*)d_in[14];
    const float* Wout = (const float*)d_in[15];
    const float* bout = (const float*)d_in[16];
    const int* ei_ap = (const int*)d_in[17];
    const int* ei_pa = (const int*)d_in[18];
    const int* ei_pp = (const int*)d_in[19];

    float* ws = (float*)d_ws;
    const size_t NB = (size_t)NNODE * 128;   // 12.8M floats
    float* B0 = ws;
    float* B1 = B0 + NB;
    float* B2 = B1 + NB;
    float* B3 = B2 + NB;
    float* A0   = B3 + NB;          // 800k floats (asrc)
    float* A1   = A0 + NNODE * 8;   // 800k floats (adst)
    float* macc = A1 + NNODE * 8;   // 256
    float* attn = macc + 256;       // 16
    int* ip = (int*)(attn + 16);
    int* offs_ap = ip; ip += NNODE + 1;
    int* offs_pa = ip; ip += NNODE + 1;
    int* offs_pp = ip; ip += NNODE + 1;
    int* cols_ap = ip; ip += NEDGE;
    int* cols_pa = ip; ip += NEDGE;
    int* cols_pp = ip; ip += NEDGE;
    int* deg     = ip; ip += NNODE;
    int* cursor  = ip; ip += NNODE;
    int* bsum    = ip; ip += 256;
    int* boff    = ip; ip += 256;
    // total ~219 MB

    const dim3 blk(256);
    const int gemmGrid = (NNODE + 127) / 128;   // 782
    const int nodeGrid = (NNODE * 8) / 256;     // 3125
    const int vecGrid  = (NNODE * 128 / 4) / 256; // 12500
    const int aggGrid  = (NNODE + 3) / 4;       // 25000
    const int scanNB   = (NNODE + 1023) / 1024; // 98

    auto build_csr = [&](const int* ei, int* offs, int* cols) {
        hipMemsetAsync(deg, 0, NNODE * 4, stream);
        hist_dst<<<(NEDGE + 255) / 256, blk, 0, stream>>>(ei, deg);
        scan_block<<<scanNB, 1024, 0, stream>>>(deg, offs, bsum, NNODE);
        scan_bsum<<<1, 64, 0, stream>>>(bsum, boff, scanNB);
        scan_add<<<scanNB, 1024, 0, stream>>>(offs, boff, NNODE);
        copy_int<<<(NNODE + 255) / 256, blk, 0, stream>>>(offs, cursor, NNODE);
        scatter_src<<<(NEDGE + 255) / 256, blk, 0, stream>>>(ei, cursor, cols);
    };

    // CSRs are layer-invariant: build once.
    build_csr(ei_ap, offs_ap, cols_ap);
    build_csr(ei_pa, offs_pa, cols_pa);
    build_csr(ei_pp, offs_pp, cols_pp);

    auto run_edge = [&](const int* offs, const int* cols,
                        const float* zmsg, const float* zdst,
                        const float* a_s, const float* a_d, float* out) {
        node_alpha<<<nodeGrid, blk, 0, stream>>>(zmsg, a_s, A0, NNODE);
        node_alpha<<<nodeGrid, blk, 0, stream>>>(zdst, a_d, A1, NNODE);
        agg_gather<<<aggGrid, blk, 0, stream>>>(offs, cols, A0, A1, zmsg, out);
    };

    // ---------------- Layer 0 ----------------
    gemm128_bias<<<gemmGrid, blk, 0, stream>>>(x_paper,  Wp_p, bp_p, B0, NNODE);  // zp
    gemm128_bias<<<gemmGrid, blk, 0, stream>>>(x_author, Wp_a, bp_a, B1, NNODE);  // za

    run_edge(offs_ap, cols_ap, B1, B0, as_ap, ad_ap, B2);   // out_ap
    run_edge(offs_pa, cols_pa, B0, B1, as_pa, ad_pa, B3);   // out_pa = new_xa; za dead
    run_edge(offs_pp, cols_pp, B0, B0, as_pp, ad_pp, B1);   // out_pp -> B1; zp dead

    hipMemsetAsync(macc, 0, 256 * 4, stream);
    score_reduce<<<gemmGrid, blk, 0, stream>>>(B2, Wk, bk, macc,       NNODE);
    score_reduce<<<gemmGrid, blk, 0, stream>>>(B1, Wk, bk, macc + 128, NNODE);
    attn_small<<<1, 128, 0, stream>>>(macc, qv, attn);
    combine2<<<vecGrid, blk, 0, stream>>>(B0, B2, B1, attn, NNODE * 32);  // new_xp -> B0

    // ---------------- Layer 1 ----------------  (pa edge type is dead code here)
    const int wo = 128 * 128, bo = 128, ao = 128;
    gemm128_bias<<<gemmGrid, blk, 0, stream>>>(B0, Wp_p + wo, bp_p + bo, B2, NNODE); // zp' -> B2
    gemm128_bias<<<gemmGrid, blk, 0, stream>>>(B3, Wp_a + wo, bp_a + bo, B1, NNODE); // za' -> B1

    run_edge(offs_ap, cols_ap, B1, B2, as_ap + ao, ad_ap + ao, B0);   // out_ap -> B0
    run_edge(offs_pp, cols_pp, B2, B2, as_pp + ao, ad_pp + ao, B3);   // out_pp -> B3

    hipMemsetAsync(macc, 0, 256 * 4, stream);
    score_reduce<<<gemmGrid, blk, 0, stream>>>(B0, Wk + wo, bk + bo, macc,       NNODE);
    score_reduce<<<gemmGrid, blk, 0, stream>>>(B3, Wk + wo, bk + bo, macc + 128, NNODE);
    attn_small<<<1, 128, 0, stream>>>(macc, qv + bo, attn);
    combine2<<<vecGrid, blk, 0, stream>>>(B1, B0, B3, attn, NNODE * 32);  // new_xp -> B1

    final_gemm<<<(NNODE + 31) / 32, blk, 0, stream>>>(B1, Wout, bout, (float*)d_out, NNODE);
}

// Round 4
// 1280.620 us; speedup vs baseline: 14.9281x; 1.1153x over previous
//
#include <hip/hip_runtime.h>

#define NHID 128
#define NHEAD 8
#define NDIM 16
#define NNODE 100000
#define NEDGE 500000
#define NEG 0.2f

typedef float4 f4;

// ---------------- register-blocked fp32 GEMM (no LDS), C[N][128] = A @ W + b ----
// Optional fused alpha outputs: ao[n*8+h] = dot(C[n, h*16:(h+1)*16], av[h*16:..])
__global__ __launch_bounds__(256) void gemm128f(
    const float* __restrict__ A, const float* __restrict__ W,
    const float* __restrict__ bias, float* __restrict__ C, int N,
    const float* __restrict__ av0, float* __restrict__ ao0,
    const float* __restrict__ av1, float* __restrict__ ao1,
    const float* __restrict__ av2, float* __restrict__ ao2,
    const float* __restrict__ av3, float* __restrict__ ao3)
{
    const int tid = threadIdx.x;
    const int tr = tid >> 4, tc = tid & 15;
    const int row0 = blockIdx.x * 128 + tr * 8;

    const float* ar[8];
    #pragma unroll
    for (int i = 0; i < 8; ++i) {
        int r = row0 + i; r = (r < N) ? r : (N - 1);
        ar[i] = A + (size_t)r * 128;
    }
    const float* wp = W + tc * 8;

    float acc[8][8];
    #pragma unroll
    for (int i = 0; i < 8; ++i)
        #pragma unroll
        for (int j = 0; j < 8; ++j) acc[i][j] = 0.f;

    for (int k0 = 0; k0 < 128; k0 += 4) {
        float xv[8][4];
        #pragma unroll
        for (int i = 0; i < 8; ++i) {
            f4 t = *reinterpret_cast<const f4*>(ar[i] + k0);
            xv[i][0] = t.x; xv[i][1] = t.y; xv[i][2] = t.z; xv[i][3] = t.w;
        }
        float wv[4][8];
        #pragma unroll
        for (int kk = 0; kk < 4; ++kk) {
            f4 w0 = *reinterpret_cast<const f4*>(wp + (k0 + kk) * 128);
            f4 w1 = *reinterpret_cast<const f4*>(wp + (k0 + kk) * 128 + 4);
            wv[kk][0]=w0.x; wv[kk][1]=w0.y; wv[kk][2]=w0.z; wv[kk][3]=w0.w;
            wv[kk][4]=w1.x; wv[kk][5]=w1.y; wv[kk][6]=w1.z; wv[kk][7]=w1.w;
        }
        #pragma unroll
        for (int kk = 0; kk < 4; ++kk)
            #pragma unroll
            for (int i = 0; i < 8; ++i) {
                float x = xv[i][kk];
                #pragma unroll
                for (int j = 0; j < 8; ++j) acc[i][j] = fmaf(x, wv[kk][j], acc[i][j]);
            }
    }

    f4 b0 = *reinterpret_cast<const f4*>(bias + tc * 8);
    f4 b1 = *reinterpret_cast<const f4*>(bias + tc * 8 + 4);
    float bv[8] = {b0.x, b0.y, b0.z, b0.w, b1.x, b1.y, b1.z, b1.w};
    #pragma unroll
    for (int i = 0; i < 8; ++i)
        #pragma unroll
        for (int j = 0; j < 8; ++j) acc[i][j] += bv[j];

    #pragma unroll
    for (int i = 0; i < 8; ++i) {
        int gr = row0 + i;
        if (gr < N) {
            f4 o0 = make_float4(acc[i][0], acc[i][1], acc[i][2], acc[i][3]);
            f4 o1 = make_float4(acc[i][4], acc[i][5], acc[i][6], acc[i][7]);
            f4* cp = reinterpret_cast<f4*>(C + (size_t)gr * 128 + tc * 8);
            cp[0] = o0; cp[1] = o1;
        }
    }

    // fused per-head alpha dots: head h = tc>>1; this thread holds 8 of its 16 dims
    const int h = tc >> 1;
    const int aoff = h * 16 + (tc & 1) * 8;
    const bool writer = ((tc & 1) == 0);
    auto do_alpha = [&](const float* av, float* ao) {
        if (ao == nullptr) return;
        f4 a0 = *reinterpret_cast<const f4*>(av + aoff);
        f4 a1 = *reinterpret_cast<const f4*>(av + aoff + 4);
        float avv[8] = {a0.x, a0.y, a0.z, a0.w, a1.x, a1.y, a1.z, a1.w};
        #pragma unroll
        for (int i = 0; i < 8; ++i) {
            float p = 0.f;
            #pragma unroll
            for (int j = 0; j < 8; ++j) p = fmaf(acc[i][j], avv[j], p);
            p += __shfl_xor(p, 1, 64);
            int gr = row0 + i;
            if (writer && gr < N) ao[gr * 8 + h] = p;
        }
    };
    do_alpha(av0, ao0);
    do_alpha(av1, ao1);
    do_alpha(av2, ao2);
    do_alpha(av3, ao3);
}

// same core; macc[c] += sum over rows of tanh(A@W + bias)[c]
__global__ __launch_bounds__(256) void score_reduce2(
    const float* __restrict__ A, const float* __restrict__ W,
    const float* __restrict__ bias, float* __restrict__ macc, int N)
{
    const int tid = threadIdx.x;
    const int tr = tid >> 4, tc = tid & 15;
    const int row0 = blockIdx.x * 128 + tr * 8;

    const float* ar[8];
    #pragma unroll
    for (int i = 0; i < 8; ++i) {
        int r = row0 + i; r = (r < N) ? r : (N - 1);
        ar[i] = A + (size_t)r * 128;
    }
    const float* wp = W + tc * 8;

    float acc[8][8];
    #pragma unroll
    for (int i = 0; i < 8; ++i)
        #pragma unroll
        for (int j = 0; j < 8; ++j) acc[i][j] = 0.f;

    for (int k0 = 0; k0 < 128; k0 += 4) {
        float xv[8][4];
        #pragma unroll
        for (int i = 0; i < 8; ++i) {
            f4 t = *reinterpret_cast<const f4*>(ar[i] + k0);
            xv[i][0] = t.x; xv[i][1] = t.y; xv[i][2] = t.z; xv[i][3] = t.w;
        }
        float wv[4][8];
        #pragma unroll
        for (int kk = 0; kk < 4; ++kk) {
            f4 w0 = *reinterpret_cast<const f4*>(wp + (k0 + kk) * 128);
            f4 w1 = *reinterpret_cast<const f4*>(wp + (k0 + kk) * 128 + 4);
            wv[kk][0]=w0.x; wv[kk][1]=w0.y; wv[kk][2]=w0.z; wv[kk][3]=w0.w;
            wv[kk][4]=w1.x; wv[kk][5]=w1.y; wv[kk][6]=w1.z; wv[kk][7]=w1.w;
        }
        #pragma unroll
        for (int kk = 0; kk < 4; ++kk)
            #pragma unroll
            for (int i = 0; i < 8; ++i) {
                float x = xv[i][kk];
                #pragma unroll
                for (int j = 0; j < 8; ++j) acc[i][j] = fmaf(x, wv[kk][j], acc[i][j]);
            }
    }

    f4 b0 = *reinterpret_cast<const f4*>(bias + tc * 8);
    f4 b1 = *reinterpret_cast<const f4*>(bias + tc * 8 + 4);
    float bv[8] = {b0.x, b0.y, b0.z, b0.w, b1.x, b1.y, b1.z, b1.w};

    float cs[8];
    #pragma unroll
    for (int j = 0; j < 8; ++j) cs[j] = 0.f;
    #pragma unroll
    for (int i = 0; i < 8; ++i) {
        int gr = row0 + i;
        if (gr < N) {
            #pragma unroll
            for (int j = 0; j < 8; ++j) cs[j] += tanhf(acc[i][j] + bv[j]);
        }
    }

    __shared__ float sm[256][8];
    #pragma unroll
    for (int j = 0; j < 8; ++j) sm[tid][j] = cs[j];
    __syncthreads();
    if (tid < 128) {
        int tcc = tid >> 3, j = tid & 7;
        float s = 0.f;
        #pragma unroll
        for (int t = 0; t < 16; ++t) s += sm[t * 16 + tcc][j];
        atomicAdd(macc + tcc * 8 + j, s);
    }
}

// ---------------- CSR build ----------------
__global__ __launch_bounds__(256) void hist_dst(const int* __restrict__ ei, int* __restrict__ deg)
{
    int e = blockIdx.x * 256 + threadIdx.x;
    if (e < NEDGE) atomicAdd(deg + ei[NEDGE + e], 1);
}

__global__ __launch_bounds__(1024) void scan_block(const int* __restrict__ deg,
    int* __restrict__ offs, int* __restrict__ bsum, int N)
{
    __shared__ int sd[1024];
    int t = threadIdx.x, i = blockIdx.x * 1024 + t;
    int v = (i < N) ? deg[i] : 0;
    sd[t] = v; __syncthreads();
    for (int o = 1; o < 1024; o <<= 1) {
        int x = (t >= o) ? sd[t - o] : 0;
        __syncthreads();
        sd[t] += x;
        __syncthreads();
    }
    if (i < N) offs[i + 1] = sd[t];
    if (t == 1023) bsum[blockIdx.x] = sd[t];
}

__global__ void scan_bsum(const int* __restrict__ bsum, int* __restrict__ boff, int nb)
{
    if (threadIdx.x == 0) {
        int run = 0;
        for (int b = 0; b < nb; ++b) { boff[b] = run; run += bsum[b]; }
    }
}

__global__ __launch_bounds__(1024) void scan_add(int* __restrict__ offs,
    const int* __restrict__ boff, int N)
{
    int i = blockIdx.x * 1024 + threadIdx.x;
    if (i == 0) offs[0] = 0;
    if (i < N) offs[i + 1] += boff[blockIdx.x];
}

__global__ __launch_bounds__(256) void copy_int(const int* __restrict__ src,
    int* __restrict__ dst, int n)
{
    int i = blockIdx.x * 256 + threadIdx.x;
    if (i < n) dst[i] = src[i];
}

__global__ __launch_bounds__(256) void scatter_src(const int* __restrict__ ei,
    int* __restrict__ cursor, int* __restrict__ cols)
{
    int e = blockIdx.x * 256 + threadIdx.x;
    if (e < NEDGE) {
        int d = ei[NEDGE + e];
        int pos = atomicAdd(cursor + d, 1);
        cols[pos] = ei[e];
    }
}

// ---------------- gather aggregation ----------------
__global__ __launch_bounds__(256) void agg_gather(
    const int* __restrict__ offs, const int* __restrict__ cols,
    const float* __restrict__ asrc, const float* __restrict__ adst,
    const float* __restrict__ z, float* __restrict__ out)
{
    int w = threadIdx.x >> 6;
    int lane = threadIdx.x & 63;
    int d = blockIdx.x * 4 + w;
    if (d >= NNODE) return;
    int h = lane >> 3;
    float ad = adst[d * 8 + h];
    int e0 = offs[d], e1 = offs[d + 1];
    float acc0 = 0.f, acc1 = 0.f, psum = 0.f;
    for (int e = e0; e < e1; ++e) {
        int s = cols[e];
        float a = asrc[s * 8 + h] + ad;
        a = (a >= 0.f) ? a : NEG * a;
        float p = __expf(a);
        float2 zv = *reinterpret_cast<const float2*>(z + (size_t)s * 128 + lane * 2);
        acc0 = fmaf(p, zv.x, acc0);
        acc1 = fmaf(p, zv.y, acc1);
        psum += p;
    }
    float inv = 1.f / (psum + 1e-16f);
    float2 o;
    o.x = fmaxf(acc0 * inv, 0.f);
    o.y = fmaxf(acc1 * inv, 0.f);
    *reinterpret_cast<float2*>(out + (size_t)d * 128 + lane * 2) = o;
}

// softmax over the two semantic scores
__global__ void attn_small(const float* __restrict__ macc,
                           const float* __restrict__ qv, float* __restrict__ attn)
{
    __shared__ float s0[128], s1[128];
    int t = threadIdx.x;
    s0[t] = macc[t] * qv[t];
    s1[t] = macc[128 + t] * qv[t];
    __syncthreads();
    if (t == 0) {
        float a = 0.f, b = 0.f;
        for (int i = 0; i < 128; ++i) { a += s0[i]; b += s1[i]; }
        a *= (1.0f / 100000.0f);
        b *= (1.0f / 100000.0f);
        float m = fmaxf(a, b);
        float ea = expf(a - m), eb = expf(b - m);
        float inv = 1.f / (ea + eb);
        attn[0] = ea * inv;
        attn[1] = eb * inv;
    }
}

// dst = attn[0]*inA + attn[1]*inB
__global__ __launch_bounds__(256) void combine2(
    float* __restrict__ dst, const float* __restrict__ inA,
    const float* __restrict__ inB, const float* __restrict__ attn, int n4)
{
    int i = blockIdx.x * 256 + threadIdx.x;
    if (i >= n4) return;
    float a0 = attn[0], a1 = attn[1];
    f4 A = reinterpret_cast<const f4*>(inA)[i];
    f4 B = reinterpret_cast<const f4*>(inB)[i];
    f4 r = make_float4(a0*A.x + a1*B.x, a0*A.y + a1*B.y,
                       a0*A.z + a1*B.z, a0*A.w + a1*B.w);
    reinterpret_cast<f4*>(dst)[i] = r;
}

// out[N][8] = X[N][128] @ W[128][8] + bias
__global__ __launch_bounds__(256) void final_gemm(
    const float* __restrict__ X, const float* __restrict__ W,
    const float* __restrict__ bias, float* __restrict__ out, int N)
{
    __shared__ float Ws[128][8];
    __shared__ __align__(16) float Xs[32][129];
    int tid = threadIdx.x;
    for (int i = tid; i < 1024; i += 256) Ws[i >> 3][i & 7] = W[i];
    int row0 = blockIdx.x * 32;
    for (int i = tid; i < 1024; i += 256) {
        int r = i >> 5, q = i & 31;
        int gr = row0 + r;
        f4 v = make_float4(0.f, 0.f, 0.f, 0.f);
        if (gr < N) v = reinterpret_cast<const f4*>(X + (size_t)gr * 128)[q];
        Xs[r][q*4] = v.x; Xs[r][q*4+1] = v.y; Xs[r][q*4+2] = v.z; Xs[r][q*4+3] = v.w;
    }
    __syncthreads();
    int r = tid >> 3, o = tid & 7;
    int gr = row0 + r;
    if (gr < N) {
        float s = bias[o];
        #pragma unroll
        for (int k = 0; k < 128; ++k) s = fmaf(Xs[r][k], Ws[k][o], s);
        out[(size_t)gr * 8 + o] = s;
    }
}

extern "C" void kernel_launch(void* const* d_in, const int* in_sizes, int n_in,
                              void* d_out, int out_size, void* d_ws, size_t ws_size,
                              hipStream_t stream) {
    const float* x_paper  = (const float*)d_in[0];
    const float* x_author = (const float*)d_in[1];
    const float* Wp_p = (const float*)d_in[2];
    const float* bp_p = (const float*)d_in[3];
    const float* Wp_a = (const float*)d_in[4];
    const float* bp_a = (const float*)d_in[5];
    const float* as_ap = (const float*)d_in[6];
    const float* ad_ap = (const float*)d_in[7];
    const float* as_pa = (const float*)d_in[8];
    const float* ad_pa = (const float*)d_in[9];
    const float* as_pp = (const float*)d_in[10];
    const float* ad_pp = (const float*)d_in[11];
    const float* Wk   = (const float*)d_in[12];
    const float* bk   = (const float*)d_in[13];
    const float* qv   = (const float*)d_in[14];
    const float* Wout = (const float*)d_in[15];
    const float* bout = (const float*)d_in[16];
    const int* ei_ap = (const int*)d_in[17];
    const int* ei_pa = (const int*)d_in[18];
    const int* ei_pp = (const int*)d_in[19];

    float* ws = (float*)d_ws;
    const size_t NB = (size_t)NNODE * 128;   // 12.8M floats
    float* B0 = ws;
    float* B1 = B0 + NB;
    float* B2 = B1 + NB;
    float* B3 = B2 + NB;
    float* p = B3 + NB;
    float* ap_s = p; p += NNODE * 8;
    float* ap_d = p; p += NNODE * 8;
    float* pa_s = p; p += NNODE * 8;
    float* pa_d = p; p += NNODE * 8;
    float* pp_s = p; p += NNODE * 8;
    float* pp_d = p; p += NNODE * 8;
    float* macc = p; p += 256;
    float* attn = p; p += 16;
    int* ip = (int*)(attn + 16);
    int* offs_ap = ip; ip += NNODE + 1;
    int* offs_pa = ip; ip += NNODE + 1;
    int* offs_pp = ip; ip += NNODE + 1;
    int* cols_ap = ip; ip += NEDGE;
    int* cols_pa = ip; ip += NEDGE;
    int* cols_pp = ip; ip += NEDGE;
    int* deg     = ip; ip += NNODE;
    int* cursor  = ip; ip += NNODE;
    int* bsum    = ip; ip += 256;
    int* boff    = ip; ip += 256;
    // total ~232 MB

    const dim3 blk(256);
    const int gemmGrid = (NNODE + 127) / 128;     // 782
    const int vecGrid  = (NNODE * 128 / 4) / 256; // 12500
    const int aggGrid  = (NNODE + 3) / 4;         // 25000
    const int scanNB   = (NNODE + 1023) / 1024;   // 98

    auto build_csr = [&](const int* ei, int* offs, int* cols) {
        hipMemsetAsync(deg, 0, NNODE * 4, stream);
        hist_dst<<<(NEDGE + 255) / 256, blk, 0, stream>>>(ei, deg);
        scan_block<<<scanNB, 1024, 0, stream>>>(deg, offs, bsum, NNODE);
        scan_bsum<<<1, 64, 0, stream>>>(bsum, boff, scanNB);
        scan_add<<<scanNB, 1024, 0, stream>>>(offs, boff, NNODE);
        copy_int<<<(NNODE + 255) / 256, blk, 0, stream>>>(offs, cursor, NNODE);
        scatter_src<<<(NEDGE + 255) / 256, blk, 0, stream>>>(ei, cursor, cols);
    };

    build_csr(ei_ap, offs_ap, cols_ap);
    build_csr(ei_pa, offs_pa, cols_pa);
    build_csr(ei_pp, offs_pp, cols_pp);

    // ---------------- Layer 0 ----------------
    // zp -> B0, fused alphas: ad_ap, as_pa, as_pp, ad_pp
    gemm128f<<<gemmGrid, blk, 0, stream>>>(x_paper, Wp_p, bp_p, B0, NNODE,
        ad_ap, ap_d, as_pa, pa_s, as_pp, pp_s, ad_pp, pp_d);
    // za -> B1, fused alphas: as_ap, ad_pa
    gemm128f<<<gemmGrid, blk, 0, stream>>>(x_author, Wp_a, bp_a, B1, NNODE,
        as_ap, ap_s, ad_pa, pa_d, nullptr, nullptr, nullptr, nullptr);

    agg_gather<<<aggGrid, blk, 0, stream>>>(offs_ap, cols_ap, ap_s, ap_d, B1, B2); // out_ap
    agg_gather<<<aggGrid, blk, 0, stream>>>(offs_pa, cols_pa, pa_s, pa_d, B0, B3); // out_pa = new_xa
    agg_gather<<<aggGrid, blk, 0, stream>>>(offs_pp, cols_pp, pp_s, pp_d, B0, B1); // out_pp

    hipMemsetAsync(macc, 0, 256 * 4, stream);
    score_reduce2<<<gemmGrid, blk, 0, stream>>>(B2, Wk, bk, macc,       NNODE);
    score_reduce2<<<gemmGrid, blk, 0, stream>>>(B1, Wk, bk, macc + 128, NNODE);
    attn_small<<<1, 128, 0, stream>>>(macc, qv, attn);
    combine2<<<vecGrid, blk, 0, stream>>>(B0, B2, B1, attn, NNODE * 32);  // new_xp -> B0

    // ---------------- Layer 1 ----------------  (pa edge type is dead code here)
    const int wo = 128 * 128, bo = 128, ao = 128;
    // zp' -> B2, fused alphas: ad_ap, as_pp, ad_pp (layer-1 vectors)
    gemm128f<<<gemmGrid, blk, 0, stream>>>(B0, Wp_p + wo, bp_p + bo, B2, NNODE,
        ad_ap + ao, ap_d, as_pp + ao, pp_s, ad_pp + ao, pp_d, nullptr, nullptr);
    // za' -> B1, fused alpha: as_ap
    gemm128f<<<gemmGrid, blk, 0, stream>>>(B3, Wp_a + wo, bp_a + bo, B1, NNODE,
        as_ap + ao, ap_s, nullptr, nullptr, nullptr, nullptr, nullptr, nullptr);

    agg_gather<<<aggGrid, blk, 0, stream>>>(offs_ap, cols_ap, ap_s, ap_d, B1, B0); // out_ap -> B0
    agg_gather<<<aggGrid, blk, 0, stream>>>(offs_pp, cols_pp, pp_s, pp_d, B2, B3); // out_pp -> B3

    hipMemsetAsync(macc, 0, 256 * 4, stream);
    score_reduce2<<<gemmGrid, blk, 0, stream>>>(B0, Wk + wo, bk + bo, macc,       NNODE);
    score_reduce2<<<gemmGrid, blk, 0, stream>>>(B3, Wk + wo, bk + bo, macc + 128, NNODE);
    attn_small<<<1, 128, 0, stream>>>(macc, qv + bo, attn);
    combine2<<<vecGrid, blk, 0, stream>>>(B1, B0, B3, attn, NNODE * 32);  // new_xp -> B1

    final_gemm<<<(NNODE + 31) / 32, blk, 0, stream>>>(B1, Wout, bout, (float*)d_out, NNODE);
}

// Round 5
// 987.783 us; speedup vs baseline: 19.3537x; 1.2965x over previous
//
#include <hip/hip_runtime.h>

#define NHID 128
#define NHEAD 8
#define NNODE 100000
#define NEDGE 500000
#define NEG 0.2f

typedef float4 f4;
typedef __attribute__((ext_vector_type(8))) short bfrag;   // 8 bf16 (4 VGPR)
typedef __attribute__((ext_vector_type(4))) float facc;    // 4 f32 acc

__device__ inline float b2f(unsigned int u) {
    return __uint_as_float(u << 16);
}
__device__ inline unsigned short f2b(float f) {
    unsigned int u = __float_as_uint(f);
    unsigned int r = (u + 0x7FFFu + ((u >> 16) & 1u)) >> 16;
    return (unsigned short)r;
}

// ---------------- prep kernels ----------------
// fp32 -> bf16, 4 elems/thread
__global__ __launch_bounds__(256) void cvt_x(const float* __restrict__ in,
                                             ushort* __restrict__ out, int n4)
{
    int i = blockIdx.x * 256 + threadIdx.x;
    if (i >= n4) return;
    f4 v = reinterpret_cast<const f4*>(in)[i];
    ushort4 o;
    o.x = f2b(v.x); o.y = f2b(v.y); o.z = f2b(v.z); o.w = f2b(v.w);
    reinterpret_cast<ushort4*>(out)[i] = o;
}

// Wt[n][k] = bf16(W[k][n]); 128x128
__global__ __launch_bounds__(256) void cvt_wt(const float* __restrict__ W,
                                              ushort* __restrict__ Wt)
{
    int i = blockIdx.x * 256 + threadIdx.x;
    if (i >= 16384) return;
    int n = i >> 7, k = i & 127;
    Wt[n * 128 + k] = f2b(W[k * 128 + n]);
}

// G[c][m] = bf16( sum_dd W[m][h*16+dd] * vp[h*16+dd] ), c = vec*8+h; bAv[c] = b.Av
__global__ __launch_bounds__(256) void build_wav(
    const float* __restrict__ W, const float* __restrict__ b,
    const float* v0, const float* v1, const float* v2, const float* v3,
    ushort* __restrict__ G, float* __restrict__ bAv)
{
    int i = blockIdx.x * 256 + threadIdx.x;
    if (i >= 4096) return;
    int c = i >> 7, m = i & 127;
    const float* vp = (c < 8) ? v0 : (c < 16) ? v1 : (c < 24) ? v2 : v3;
    int h = c & 7;
    float s = 0.f;
    if (vp) {
        #pragma unroll
        for (int dd = 0; dd < 16; ++dd)
            s = fmaf(W[m * 128 + h * 16 + dd], vp[h * 16 + dd], s);
    }
    G[c * 128 + m] = f2b(s);
    if (m == 0) {
        float t = 0.f;
        if (vp) {
            #pragma unroll
            for (int dd = 0; dd < 16; ++dd)
                t = fmaf(b[h * 16 + dd], vp[h * 16 + dd], t);
        }
        bAv[c] = t;
    }
}

// ---------------- MFMA GEMM: C_bf16[N][128] = A_bf16 @ W + bias; fused alpha ----
// Wt: [n][k] bf16. G: [c][m] bf16 (alpha = A @ G + bAv). 4 waves, wave = 32 rows.
__global__ __launch_bounds__(256) void gemm_mfma(
    const ushort* __restrict__ A, const ushort* __restrict__ Wt,
    const float* __restrict__ bias, ushort* __restrict__ C, int N,
    const ushort* __restrict__ G, const float* __restrict__ bAv,
    float* __restrict__ ao0, float* __restrict__ ao1,
    float* __restrict__ ao2, float* __restrict__ ao3)
{
    const int tid = threadIdx.x;
    const int l = tid & 63, w = tid >> 6;
    const int lr = l & 15, lg = l >> 4;
    const int rw0 = blockIdx.x * 128 + w * 32;

    const ushort* aptr[2];
    #pragma unroll
    for (int i = 0; i < 2; ++i) {
        int r = rw0 + i * 16 + lr; r = (r < N) ? r : (N - 1);
        aptr[i] = A + (size_t)r * 128 + lg * 8;
    }
    const ushort* bptr[8];
    #pragma unroll
    for (int j = 0; j < 8; ++j)
        bptr[j] = Wt + (j * 16 + lr) * 128 + lg * 8;
    const ushort* gptr[2];
    #pragma unroll
    for (int jt = 0; jt < 2; ++jt)
        gptr[jt] = G + (jt * 16 + lr) * 128 + lg * 8;

    facc accC[2][8];
    facc accP[2][2];
    #pragma unroll
    for (int i = 0; i < 2; ++i) {
        #pragma unroll
        for (int j = 0; j < 8; ++j) accC[i][j] = (facc){0.f, 0.f, 0.f, 0.f};
        #pragma unroll
        for (int jt = 0; jt < 2; ++jt) accP[i][jt] = (facc){0.f, 0.f, 0.f, 0.f};
    }

    #pragma unroll
    for (int kk = 0; kk < 4; ++kk) {
        bfrag av_[2], bv_[8], gv_[2];
        #pragma unroll
        for (int i = 0; i < 2; ++i)
            av_[i] = *reinterpret_cast<const bfrag*>(aptr[i] + kk * 32);
        #pragma unroll
        for (int j = 0; j < 8; ++j)
            bv_[j] = *reinterpret_cast<const bfrag*>(bptr[j] + kk * 32);
        #pragma unroll
        for (int jt = 0; jt < 2; ++jt)
            gv_[jt] = *reinterpret_cast<const bfrag*>(gptr[jt] + kk * 32);
        #pragma unroll
        for (int i = 0; i < 2; ++i) {
            #pragma unroll
            for (int j = 0; j < 8; ++j)
                accC[i][j] = __builtin_amdgcn_mfma_f32_16x16x32_bf16(
                    av_[i], bv_[j], accC[i][j], 0, 0, 0);
            #pragma unroll
            for (int jt = 0; jt < 2; ++jt)
                accP[i][jt] = __builtin_amdgcn_mfma_f32_16x16x32_bf16(
                    av_[i], gv_[jt], accP[i][jt], 0, 0, 0);
        }
    }

    // C store: row = rw0 + i*16 + lg*4 + r; col = j*16 + lr
    #pragma unroll
    for (int j = 0; j < 8; ++j) {
        float bj = bias[j * 16 + lr];
        #pragma unroll
        for (int i = 0; i < 2; ++i) {
            #pragma unroll
            for (int r = 0; r < 4; ++r) {
                int row = rw0 + i * 16 + lg * 4 + r;
                if (row < N)
                    C[(size_t)row * 128 + j * 16 + lr] = f2b(accP[0][0][0] * 0.f + accC[i][j][r] + bj);
            }
        }
    }

    // alpha store: c = jt*16 + lr; vec = c>>3; h = c&7
    #pragma unroll
    for (int jt = 0; jt < 2; ++jt) {
        int c = jt * 16 + lr;
        int vec = c >> 3, h = c & 7;
        float* ao = (vec == 0) ? ao0 : (vec == 1) ? ao1 : (vec == 2) ? ao2 : ao3;
        if (ao == nullptr) continue;
        float bv = bAv[c];
        #pragma unroll
        for (int i = 0; i < 2; ++i) {
            #pragma unroll
            for (int r = 0; r < 4; ++r) {
                int row = rw0 + i * 16 + lg * 4 + r;
                if (row < N) ao[row * 8 + h] = accP[i][jt][r] + bv;
            }
        }
    }
}

// ---------------- MFMA score: macc[c] += colsum tanh(A@Wk + bk) ----------------
__global__ __launch_bounds__(256) void score_mfma(
    const ushort* __restrict__ A, const ushort* __restrict__ Wt,
    const float* __restrict__ bias, float* __restrict__ macc, int N)
{
    const int tid = threadIdx.x;
    const int l = tid & 63, w = tid >> 6;
    const int lr = l & 15, lg = l >> 4;
    const int rw0 = blockIdx.x * 128 + w * 32;

    const ushort* aptr[2];
    #pragma unroll
    for (int i = 0; i < 2; ++i) {
        int r = rw0 + i * 16 + lr; r = (r < N) ? r : (N - 1);
        aptr[i] = A + (size_t)r * 128 + lg * 8;
    }
    const ushort* bptr[8];
    #pragma unroll
    for (int j = 0; j < 8; ++j)
        bptr[j] = Wt + (j * 16 + lr) * 128 + lg * 8;

    facc acc[2][8];
    #pragma unroll
    for (int i = 0; i < 2; ++i)
        #pragma unroll
        for (int j = 0; j < 8; ++j) acc[i][j] = (facc){0.f, 0.f, 0.f, 0.f};

    #pragma unroll
    for (int kk = 0; kk < 4; ++kk) {
        bfrag av_[2], bv_[8];
        #pragma unroll
        for (int i = 0; i < 2; ++i)
            av_[i] = *reinterpret_cast<const bfrag*>(aptr[i] + kk * 32);
        #pragma unroll
        for (int j = 0; j < 8; ++j)
            bv_[j] = *reinterpret_cast<const bfrag*>(bptr[j] + kk * 32);
        #pragma unroll
        for (int i = 0; i < 2; ++i)
            #pragma unroll
            for (int j = 0; j < 8; ++j)
                acc[i][j] = __builtin_amdgcn_mfma_f32_16x16x32_bf16(
                    av_[i], bv_[j], acc[i][j], 0, 0, 0);
    }

    __shared__ float sred[4][128];
    #pragma unroll
    for (int j = 0; j < 8; ++j) {
        float bj = bias[j * 16 + lr];
        float s = 0.f;
        #pragma unroll
        for (int i = 0; i < 2; ++i) {
            #pragma unroll
            for (int r = 0; r < 4; ++r) {
                int row = rw0 + i * 16 + lg * 4 + r;
                if (row < N) s += tanhf(acc[i][j][r] + bj);
            }
        }
        s += __shfl_xor(s, 16, 64);
        s += __shfl_xor(s, 32, 64);
        if (lg == 0) sred[w][j * 16 + lr] = s;
    }
    __syncthreads();
    if (tid < 128) {
        float t = sred[0][tid] + sred[1][tid] + sred[2][tid] + sred[3][tid];
        atomicAdd(macc + tid, t);
    }
}

// ---------------- CSR build ----------------
__global__ __launch_bounds__(256) void hist_dst(const int* __restrict__ ei, int* __restrict__ deg)
{
    int e = blockIdx.x * 256 + threadIdx.x;
    if (e < NEDGE) atomicAdd(deg + ei[NEDGE + e], 1);
}

__global__ __launch_bounds__(1024) void scan_block(const int* __restrict__ deg,
    int* __restrict__ offs, int* __restrict__ bsum, int N)
{
    __shared__ int sd[1024];
    int t = threadIdx.x, i = blockIdx.x * 1024 + t;
    int v = (i < N) ? deg[i] : 0;
    sd[t] = v; __syncthreads();
    for (int o = 1; o < 1024; o <<= 1) {
        int x = (t >= o) ? sd[t - o] : 0;
        __syncthreads();
        sd[t] += x;
        __syncthreads();
    }
    if (i < N) offs[i + 1] = sd[t];
    if (t == 1023) bsum[blockIdx.x] = sd[t];
}

__global__ void scan_bsum(const int* __restrict__ bsum, int* __restrict__ boff, int nb)
{
    if (threadIdx.x == 0) {
        int run = 0;
        for (int b = 0; b < nb; ++b) { boff[b] = run; run += bsum[b]; }
    }
}

__global__ __launch_bounds__(1024) void scan_add(int* __restrict__ offs,
    const int* __restrict__ boff, int N)
{
    int i = blockIdx.x * 1024 + threadIdx.x;
    if (i == 0) offs[0] = 0;
    if (i < N) offs[i + 1] += boff[blockIdx.x];
}

__global__ __launch_bounds__(256) void copy_int(const int* __restrict__ src,
    int* __restrict__ dst, int n)
{
    int i = blockIdx.x * 256 + threadIdx.x;
    if (i < n) dst[i] = src[i];
}

__global__ __launch_bounds__(256) void scatter_src(const int* __restrict__ ei,
    int* __restrict__ cursor, int* __restrict__ cols)
{
    int e = blockIdx.x * 256 + threadIdx.x;
    if (e < NEDGE) {
        int d = ei[NEDGE + e];
        int pos = atomicAdd(cursor + d, 1);
        cols[pos] = ei[e];
    }
}

// ---------------- gather aggregation (bf16 z/out) ----------------
__global__ __launch_bounds__(256) void agg_gather(
    const int* __restrict__ offs, const int* __restrict__ cols,
    const float* __restrict__ asrc, const float* __restrict__ adst,
    const ushort* __restrict__ z, ushort* __restrict__ out)
{
    int w = threadIdx.x >> 6;
    int lane = threadIdx.x & 63;
    int d = blockIdx.x * 4 + w;
    if (d >= NNODE) return;
    int h = lane >> 3;
    float ad = adst[d * 8 + h];
    int e0 = offs[d], e1 = offs[d + 1];
    float acc0 = 0.f, acc1 = 0.f, psum = 0.f;
    for (int e = e0; e < e1; ++e) {
        int s = cols[e];
        float a = asrc[s * 8 + h] + ad;
        a = (a >= 0.f) ? a : NEG * a;
        float p = __expf(a);
        unsigned int zp = *reinterpret_cast<const unsigned int*>(z + (size_t)s * 128 + lane * 2);
        acc0 = fmaf(p, b2f(zp & 0xffffu), acc0);
        acc1 = fmaf(p, b2f(zp >> 16), acc1);
        psum += p;
    }
    float inv = 1.f / (psum + 1e-16f);
    float o0 = fmaxf(acc0 * inv, 0.f);
    float o1 = fmaxf(acc1 * inv, 0.f);
    unsigned int packed = (unsigned int)f2b(o0) | ((unsigned int)f2b(o1) << 16);
    *reinterpret_cast<unsigned int*>(out + (size_t)d * 128 + lane * 2) = packed;
}

// softmax over the two semantic scores
__global__ void attn_small(const float* __restrict__ macc,
                           const float* __restrict__ qv, float* __restrict__ attn)
{
    __shared__ float s0[128], s1[128];
    int t = threadIdx.x;
    s0[t] = macc[t] * qv[t];
    s1[t] = macc[128 + t] * qv[t];
    __syncthreads();
    if (t == 0) {
        float a = 0.f, b = 0.f;
        for (int i = 0; i < 128; ++i) { a += s0[i]; b += s1[i]; }
        a *= (1.0f / 100000.0f);
        b *= (1.0f / 100000.0f);
        float m = fmaxf(a, b);
        float ea = expf(a - m), eb = expf(b - m);
        float inv = 1.f / (ea + eb);
        attn[0] = ea * inv;
        attn[1] = eb * inv;
    }
}

// dst = attn[0]*inA + attn[1]*inB, bf16, 8 elems/thread
__global__ __launch_bounds__(256) void combine2b(
    ushort* __restrict__ dst, const ushort* __restrict__ inA,
    const ushort* __restrict__ inB, const float* __restrict__ attn, int n8)
{
    int i = blockIdx.x * 256 + threadIdx.x;
    if (i >= n8) return;
    float a0 = attn[0], a1 = attn[1];
    uint4 A = reinterpret_cast<const uint4*>(inA)[i];
    uint4 B = reinterpret_cast<const uint4*>(inB)[i];
    auto mix = [&](unsigned int a, unsigned int b) -> unsigned int {
        float lo = a0 * b2f(a & 0xffffu) + a1 * b2f(b & 0xffffu);
        float hi = a0 * b2f(a >> 16) + a1 * b2f(b >> 16);
        return (unsigned int)f2b(lo) | ((unsigned int)f2b(hi) << 16);
    };
    uint4 R;
    R.x = mix(A.x, B.x); R.y = mix(A.y, B.y);
    R.z = mix(A.z, B.z); R.w = mix(A.w, B.w);
    reinterpret_cast<uint4*>(dst)[i] = R;
}

// out[N][8] = X_bf16[N][128] @ W[128][8] + bias
__global__ __launch_bounds__(256) void final_gemm_b(
    const ushort* __restrict__ X, const float* __restrict__ W,
    const float* __restrict__ bias, float* __restrict__ out, int N)
{
    __shared__ float Ws[128][8];
    __shared__ __align__(16) float Xs[32][129];
    int tid = threadIdx.x;
    for (int i = tid; i < 1024; i += 256) Ws[i >> 3][i & 7] = W[i];
    int row0 = blockIdx.x * 32;
    for (int i = tid; i < 512; i += 256) {
        int r = i >> 4, q = i & 15;
        int gr = row0 + r;
        uint4 v = make_uint4(0, 0, 0, 0);
        if (gr < N) v = reinterpret_cast<const uint4*>(X + (size_t)gr * 128)[q];
        int c = q * 8;
        Xs[r][c+0] = b2f(v.x & 0xffffu); Xs[r][c+1] = b2f(v.x >> 16);
        Xs[r][c+2] = b2f(v.y & 0xffffu); Xs[r][c+3] = b2f(v.y >> 16);
        Xs[r][c+4] = b2f(v.z & 0xffffu); Xs[r][c+5] = b2f(v.z >> 16);
        Xs[r][c+6] = b2f(v.w & 0xffffu); Xs[r][c+7] = b2f(v.w >> 16);
    }
    __syncthreads();
    int r = tid >> 3, o = tid & 7;
    int gr = row0 + r;
    if (gr < N) {
        float s = bias[o];
        #pragma unroll
        for (int k = 0; k < 128; ++k) s = fmaf(Xs[r][k], Ws[k][o], s);
        out[(size_t)gr * 8 + o] = s;
    }
}

extern "C" void kernel_launch(void* const* d_in, const int* in_sizes, int n_in,
                              void* d_out, int out_size, void* d_ws, size_t ws_size,
                              hipStream_t stream) {
    const float* x_paper  = (const float*)d_in[0];
    const float* x_author = (const float*)d_in[1];
    const float* Wp_p = (const float*)d_in[2];
    const float* bp_p = (const float*)d_in[3];
    const float* Wp_a = (const float*)d_in[4];
    const float* bp_a = (const float*)d_in[5];
    const float* as_ap = (const float*)d_in[6];
    const float* ad_ap = (const float*)d_in[7];
    const float* as_pa = (const float*)d_in[8];
    const float* ad_pa = (const float*)d_in[9];
    const float* as_pp = (const float*)d_in[10];
    const float* ad_pp = (const float*)d_in[11];
    const float* Wk   = (const float*)d_in[12];
    const float* bk   = (const float*)d_in[13];
    const float* qv   = (const float*)d_in[14];
    const float* Wout = (const float*)d_in[15];
    const float* bout = (const float*)d_in[16];
    const int* ei_ap = (const int*)d_in[17];
    const int* ei_pa = (const int*)d_in[18];
    const int* ei_pp = (const int*)d_in[19];

    const size_t NB = (size_t)NNODE * 128;   // 12.8M elems
    ushort* XP = (ushort*)d_ws;
    ushort* XA = XP + NB;
    ushort* Z0 = XA + NB;
    ushort* Z1 = Z0 + NB;
    ushort* Z2 = Z1 + NB;
    ushort* Z3 = Z2 + NB;
    float* fp = (float*)(Z3 + NB);
    float* ap_s = fp; fp += NNODE * 8;
    float* ap_d = fp; fp += NNODE * 8;
    float* pa_s = fp; fp += NNODE * 8;
    float* pa_d = fp; fp += NNODE * 8;
    float* pp_s = fp; fp += NNODE * 8;
    float* pp_d = fp; fp += NNODE * 8;
    float* macc = fp; fp += 256;
    float* attn = fp; fp += 16;
    float* bAv_p0 = fp; fp += 32;
    float* bAv_a0 = fp; fp += 32;
    float* bAv_p1 = fp; fp += 32;
    float* bAv_a1 = fp; fp += 32;
    ushort* up = (ushort*)fp;
    ushort* WtP0 = up; up += 16384;
    ushort* WtA0 = up; up += 16384;
    ushort* WtP1 = up; up += 16384;
    ushort* WtA1 = up; up += 16384;
    ushort* WtK0 = up; up += 16384;
    ushort* WtK1 = up; up += 16384;
    ushort* G_p0 = up; up += 4096;
    ushort* G_a0 = up; up += 4096;
    ushort* G_p1 = up; up += 4096;
    ushort* G_a1 = up; up += 4096;
    int* ip = (int*)(((size_t)up + 15) & ~(size_t)15);
    int* cols_ap = ip; ip += NEDGE;
    int* cols_pa = ip; ip += NEDGE;
    int* cols_pp = ip; ip += NEDGE;
    int* offs_ap = ip; ip += NNODE + 1;
    int* offs_pa = ip; ip += NNODE + 1;
    int* offs_pp = ip; ip += NNODE + 1;
    int* deg     = ip; ip += NNODE;
    int* cursor  = ip; ip += NNODE;
    int* bsum    = ip; ip += 256;
    int* boff    = ip; ip += 256;
    // total ~181 MB

    const dim3 blk(256);
    const int gemmGrid = (NNODE + 127) / 128;     // 782
    const int aggGrid  = (NNODE + 3) / 4;         // 25000
    const int cmbGrid  = (NNODE * 16 + 255) / 256;// 6250
    const int cvtGrid  = (NNODE * 32 + 255) / 256;// 12500
    const int scanNB   = (NNODE + 1023) / 1024;   // 98
    const int wo = 128 * 128, bo = 128, ao = 128;

    // ---- prep: conversions, weight transposes, fused alpha matrices, CSRs ----
    cvt_x<<<cvtGrid, blk, 0, stream>>>(x_paper,  XP, NNODE * 32);
    cvt_x<<<cvtGrid, blk, 0, stream>>>(x_author, XA, NNODE * 32);
    cvt_wt<<<64, blk, 0, stream>>>(Wp_p,      WtP0);
    cvt_wt<<<64, blk, 0, stream>>>(Wp_a,      WtA0);
    cvt_wt<<<64, blk, 0, stream>>>(Wp_p + wo, WtP1);
    cvt_wt<<<64, blk, 0, stream>>>(Wp_a + wo, WtA1);
    cvt_wt<<<64, blk, 0, stream>>>(Wk,        WtK0);
    cvt_wt<<<64, blk, 0, stream>>>(Wk + wo,   WtK1);
    build_wav<<<16, blk, 0, stream>>>(Wp_p, bp_p, ad_ap, as_pa, as_pp, ad_pp, G_p0, bAv_p0);
    build_wav<<<16, blk, 0, stream>>>(Wp_a, bp_a, as_ap, ad_pa, nullptr, nullptr, G_a0, bAv_a0);
    build_wav<<<16, blk, 0, stream>>>(Wp_p + wo, bp_p + bo, ad_ap + ao, as_pp + ao, ad_pp + ao, nullptr, G_p1, bAv_p1);
    build_wav<<<16, blk, 0, stream>>>(Wp_a + wo, bp_a + bo, as_ap + ao, nullptr, nullptr, nullptr, G_a1, bAv_a1);

    auto build_csr = [&](const int* ei, int* offs, int* cols) {
        hipMemsetAsync(deg, 0, NNODE * 4, stream);
        hist_dst<<<(NEDGE + 255) / 256, blk, 0, stream>>>(ei, deg);
        scan_block<<<scanNB, 1024, 0, stream>>>(deg, offs, bsum, NNODE);
        scan_bsum<<<1, 64, 0, stream>>>(bsum, boff, scanNB);
        scan_add<<<scanNB, 1024, 0, stream>>>(offs, boff, NNODE);
        copy_int<<<(NNODE + 255) / 256, blk, 0, stream>>>(offs, cursor, NNODE);
        scatter_src<<<(NEDGE + 255) / 256, blk, 0, stream>>>(ei, cursor, cols);
    };
    build_csr(ei_ap, offs_ap, cols_ap);
    build_csr(ei_pa, offs_pa, cols_pa);
    build_csr(ei_pp, offs_pp, cols_pp);

    // ---------------- Layer 0 ----------------
    gemm_mfma<<<gemmGrid, blk, 0, stream>>>(XP, WtP0, bp_p, Z0, NNODE,
        G_p0, bAv_p0, ap_d, pa_s, pp_s, pp_d);
    gemm_mfma<<<gemmGrid, blk, 0, stream>>>(XA, WtA0, bp_a, Z1, NNODE,
        G_a0, bAv_a0, ap_s, pa_d, nullptr, nullptr);

    agg_gather<<<aggGrid, blk, 0, stream>>>(offs_ap, cols_ap, ap_s, ap_d, Z1, Z2); // out_ap
    agg_gather<<<aggGrid, blk, 0, stream>>>(offs_pa, cols_pa, pa_s, pa_d, Z0, Z3); // out_pa = new_xa
    agg_gather<<<aggGrid, blk, 0, stream>>>(offs_pp, cols_pp, pp_s, pp_d, Z0, Z1); // out_pp

    hipMemsetAsync(macc, 0, 256 * 4, stream);
    score_mfma<<<gemmGrid, blk, 0, stream>>>(Z2, WtK0, bk, macc,       NNODE);
    score_mfma<<<gemmGrid, blk, 0, stream>>>(Z1, WtK0, bk, macc + 128, NNODE);
    attn_small<<<1, 128, 0, stream>>>(macc, qv, attn);
    combine2b<<<cmbGrid, blk, 0, stream>>>(Z0, Z2, Z1, attn, NNODE * 16); // new_xp -> Z0

    // ---------------- Layer 1 ----------------  (pa edge type dead here)
    gemm_mfma<<<gemmGrid, blk, 0, stream>>>(Z0, WtP1, bp_p + bo, Z2, NNODE,
        G_p1, bAv_p1, ap_d, pp_s, pp_d, nullptr);
    gemm_mfma<<<gemmGrid, blk, 0, stream>>>(Z3, WtA1, bp_a + bo, Z1, NNODE,
        G_a1, bAv_a1, ap_s, nullptr, nullptr, nullptr);

    agg_gather<<<aggGrid, blk, 0, stream>>>(offs_ap, cols_ap, ap_s, ap_d, Z1, Z0); // out_ap -> Z0
    agg_gather<<<aggGrid, blk, 0, stream>>>(offs_pp, cols_pp, pp_s, pp_d, Z2, Z3); // out_pp -> Z3

    hipMemsetAsync(macc, 0, 256 * 4, stream);
    score_mfma<<<gemmGrid, blk, 0, stream>>>(Z0, WtK1, bk + bo, macc,       NNODE);
    score_mfma<<<gemmGrid, blk, 0, stream>>>(Z3, WtK1, bk + bo, macc + 128, NNODE);
    attn_small<<<1, 128, 0, stream>>>(macc, qv + bo, attn);
    combine2b<<<cmbGrid, blk, 0, stream>>>(Z1, Z0, Z3, attn, NNODE * 16); // new_xp -> Z1

    final_gemm_b<<<(NNODE + 31) / 32, blk, 0, stream>>>(Z1, Wout, bout, (float*)d_out, NNODE);
}

// Round 6
// 862.923 us; speedup vs baseline: 22.1540x; 1.1447x over previous
//
#include <hip/hip_runtime.h>

#define NHID 128
#define NHEAD 8
#define NNODE 100000
#define NEDGE 500000
#define NEG 0.2f

typedef float4 f4;
typedef __attribute__((ext_vector_type(8))) short bfrag;   // 8 bf16 (4 VGPR)
typedef __attribute__((ext_vector_type(4))) float facc;    // 4 f32 acc

__device__ inline float b2f(unsigned int u) {
    return __uint_as_float(u << 16);
}
__device__ inline unsigned short f2b(float f) {
    unsigned int u = __float_as_uint(f);
    unsigned int r = (u + 0x7FFFu + ((u >> 16) & 1u)) >> 16;
    return (unsigned short)r;
}

// ---------------- prep kernels ----------------
// fp32 -> bf16, 4 elems/thread
__global__ __launch_bounds__(256) void cvt_x(const float* __restrict__ in,
                                             ushort* __restrict__ out, int n4)
{
    int i = blockIdx.x * 256 + threadIdx.x;
    if (i >= n4) return;
    f4 v = reinterpret_cast<const f4*>(in)[i];
    ushort4 o;
    o.x = f2b(v.x); o.y = f2b(v.y); o.z = f2b(v.z); o.w = f2b(v.w);
    reinterpret_cast<ushort4*>(out)[i] = o;
}

// frag-major W^T: WtT[(((j*4+kk)*64 + l)*8 + e] = W[kk*32+(l>>4)*8+e][j*16+(l&15)]
__global__ __launch_bounds__(256) void cvt_wt_fm(const float* __restrict__ W,
                                                 ushort* __restrict__ WtT)
{
    int i = blockIdx.x * 256 + threadIdx.x;
    if (i >= 16384) return;
    int fi = i >> 3, e = i & 7;
    int jk = fi >> 6, l = fi & 63;
    int j = jk >> 2, kk = jk & 3;
    int lr = l & 15, lg = l >> 4;
    int n = j * 16 + lr;
    int k = kk * 32 + lg * 8 + e;
    WtT[i] = f2b(W[k * 128 + n]);
}

// frag-major G: GT[((jt*4+kk)*64 + l)*8 + e] = G_c[m], c=jt*16+(l&15), m=kk*32+(l>>4)*8+e
// G_c[m] = sum_dd W[m][h*16+dd]*vp[h*16+dd]; bAv[c] = b.Av
__global__ __launch_bounds__(256) void build_wav(
    const float* __restrict__ W, const float* __restrict__ b,
    const float* v0, const float* v1, const float* v2, const float* v3,
    ushort* __restrict__ GT, float* __restrict__ bAv)
{
    int i = blockIdx.x * 256 + threadIdx.x;
    if (i >= 4096) return;
    int fi = i >> 3, e = i & 7;
    int jk = fi >> 6, l = fi & 63;
    int jt = jk >> 2, kk = jk & 3;
    int lr = l & 15, lg = l >> 4;
    int c = jt * 16 + lr;
    int m = kk * 32 + lg * 8 + e;
    int vec = c >> 3, h = c & 7;
    const float* vp = (vec == 0) ? v0 : (vec == 1) ? v1 : (vec == 2) ? v2 : v3;
    float s = 0.f;
    if (vp) {
        #pragma unroll
        for (int dd = 0; dd < 16; ++dd)
            s = fmaf(W[m * 128 + h * 16 + dd], vp[h * 16 + dd], s);
    }
    GT[i] = f2b(s);
    if (i < 32) {
        int cc = i;
        int vv = cc >> 3, hh = cc & 7;
        const float* vq = (vv == 0) ? v0 : (vv == 1) ? v1 : (vv == 2) ? v2 : v3;
        float t = 0.f;
        if (vq) {
            #pragma unroll
            for (int dd = 0; dd < 16; ++dd)
                t = fmaf(b[hh * 16 + dd], vq[hh * 16 + dd], t);
        }
        bAv[cc] = t;
    }
}

// ---------------- dual MFMA GEMM with LDS-staged W/G ----------------
struct GemmArgs {
    const ushort* A;
    const ushort* WtT;   // frag-major, 16384 shorts
    const ushort* GT;    // frag-major, 4096 shorts
    const float* bias;
    const float* bAv;
    ushort* C;
    float* ao0; float* ao1; float* ao2; float* ao3;
};

__global__ __launch_bounds__(256) void gemm_mfma_dual(
    GemmArgs g0, GemmArgs g1, int nblk0, int N)
{
    __shared__ uint4 sm[2560];              // 32KB Wt + 8KB G
    const int bid = blockIdx.x;
    const GemmArgs& ga = (bid < nblk0) ? g0 : g1;
    const int bb = (bid < nblk0) ? bid : bid - nblk0;

    const int tid = threadIdx.x;
    const int l = tid & 63, w = tid >> 6;
    const int lr = l & 15, lg = l >> 4;
    const int rw0 = bb * 128 + w * 32;

    // stage loads (W: 8 uint4/thread, G: 2 uint4/thread)
    uint4 wreg[8], greg[2];
    {
        const uint4* ws = reinterpret_cast<const uint4*>(ga.WtT);
        const uint4* gs = reinterpret_cast<const uint4*>(ga.GT);
        #pragma unroll
        for (int i = 0; i < 8; ++i) wreg[i] = ws[tid + i * 256];
        #pragma unroll
        for (int i = 0; i < 2; ++i) greg[i] = gs[tid + i * 256];
    }

    // hoisted A fragment loads (8 independent)
    bfrag av_[2][4];
    {
        const ushort* aptr[2];
        #pragma unroll
        for (int i = 0; i < 2; ++i) {
            int r = rw0 + i * 16 + lr; r = (r < N) ? r : (N - 1);
            aptr[i] = ga.A + (size_t)r * 128 + lg * 8;
        }
        #pragma unroll
        for (int i = 0; i < 2; ++i)
            #pragma unroll
            for (int kk = 0; kk < 4; ++kk)
                av_[i][kk] = *reinterpret_cast<const bfrag*>(aptr[i] + kk * 32);
    }

    #pragma unroll
    for (int i = 0; i < 8; ++i) sm[tid + i * 256] = wreg[i];
    #pragma unroll
    for (int i = 0; i < 2; ++i) sm[2048 + tid + i * 256] = greg[i];
    __syncthreads();

    const ushort* WtL = reinterpret_cast<const ushort*>(sm);
    const ushort* GL  = WtL + 16384;

    facc accC[2][8];
    facc accP[2][2];
    #pragma unroll
    for (int i = 0; i < 2; ++i) {
        #pragma unroll
        for (int j = 0; j < 8; ++j) accC[i][j] = (facc){0.f, 0.f, 0.f, 0.f};
        #pragma unroll
        for (int jt = 0; jt < 2; ++jt) accP[i][jt] = (facc){0.f, 0.f, 0.f, 0.f};
    }

    #pragma unroll
    for (int kk = 0; kk < 4; ++kk) {
        #pragma unroll
        for (int j = 0; j < 8; ++j) {
            bfrag bv = *reinterpret_cast<const bfrag*>(WtL + ((j * 4 + kk) * 64 + l) * 8);
            #pragma unroll
            for (int i = 0; i < 2; ++i)
                accC[i][j] = __builtin_amdgcn_mfma_f32_16x16x32_bf16(
                    av_[i][kk], bv, accC[i][j], 0, 0, 0);
        }
        #pragma unroll
        for (int jt = 0; jt < 2; ++jt) {
            bfrag gv = *reinterpret_cast<const bfrag*>(GL + ((jt * 4 + kk) * 64 + l) * 8);
            #pragma unroll
            for (int i = 0; i < 2; ++i)
                accP[i][jt] = __builtin_amdgcn_mfma_f32_16x16x32_bf16(
                    av_[i][kk], gv, accP[i][jt], 0, 0, 0);
        }
    }

    // C store: row = rw0 + i*16 + lg*4 + r; col = j*16 + lr
    #pragma unroll
    for (int j = 0; j < 8; ++j) {
        float bj = ga.bias[j * 16 + lr];
        #pragma unroll
        for (int i = 0; i < 2; ++i) {
            #pragma unroll
            for (int r = 0; r < 4; ++r) {
                int row = rw0 + i * 16 + lg * 4 + r;
                if (row < N)
                    ga.C[(size_t)row * 128 + j * 16 + lr] = f2b(accC[i][j][r] + bj);
            }
        }
    }

    // alpha store
    #pragma unroll
    for (int jt = 0; jt < 2; ++jt) {
        int c = jt * 16 + lr;
        int vec = c >> 3, h = c & 7;
        float* ao = (vec == 0) ? ga.ao0 : (vec == 1) ? ga.ao1 : (vec == 2) ? ga.ao2 : ga.ao3;
        if (ao == nullptr) continue;
        float bv = ga.bAv[c];
        #pragma unroll
        for (int i = 0; i < 2; ++i) {
            #pragma unroll
            for (int r = 0; r < 4; ++r) {
                int row = rw0 + i * 16 + lg * 4 + r;
                if (row < N) ao[row * 8 + h] = accP[i][jt][r] + bv;
            }
        }
    }
}

// ---------------- dual MFMA score: macc[half*128+c] += colsum tanh(A@Wk + bk) ----
__global__ __launch_bounds__(256) void score_mfma_dual(
    const ushort* __restrict__ A0, const ushort* __restrict__ A1,
    const ushort* __restrict__ WtT, const float* __restrict__ bias,
    float* __restrict__ macc, int nblk0, int N)
{
    __shared__ uint4 sm[2048];              // 32KB Wt
    __shared__ float sred[4][128];
    const int bid = blockIdx.x;
    const ushort* A = (bid < nblk0) ? A0 : A1;
    float* mc = macc + ((bid < nblk0) ? 0 : 128);
    const int bb = (bid < nblk0) ? bid : bid - nblk0;

    const int tid = threadIdx.x;
    const int l = tid & 63, w = tid >> 6;
    const int lr = l & 15, lg = l >> 4;
    const int rw0 = bb * 128 + w * 32;

    uint4 wreg[8];
    {
        const uint4* ws = reinterpret_cast<const uint4*>(WtT);
        #pragma unroll
        for (int i = 0; i < 8; ++i) wreg[i] = ws[tid + i * 256];
    }

    bfrag av_[2][4];
    {
        const ushort* aptr[2];
        #pragma unroll
        for (int i = 0; i < 2; ++i) {
            int r = rw0 + i * 16 + lr; r = (r < N) ? r : (N - 1);
            aptr[i] = A + (size_t)r * 128 + lg * 8;
        }
        #pragma unroll
        for (int i = 0; i < 2; ++i)
            #pragma unroll
            for (int kk = 0; kk < 4; ++kk)
                av_[i][kk] = *reinterpret_cast<const bfrag*>(aptr[i] + kk * 32);
    }

    #pragma unroll
    for (int i = 0; i < 8; ++i) sm[tid + i * 256] = wreg[i];
    __syncthreads();

    const ushort* WtL = reinterpret_cast<const ushort*>(sm);

    facc acc[2][8];
    #pragma unroll
    for (int i = 0; i < 2; ++i)
        #pragma unroll
        for (int j = 0; j < 8; ++j) acc[i][j] = (facc){0.f, 0.f, 0.f, 0.f};

    #pragma unroll
    for (int kk = 0; kk < 4; ++kk) {
        #pragma unroll
        for (int j = 0; j < 8; ++j) {
            bfrag bv = *reinterpret_cast<const bfrag*>(WtL + ((j * 4 + kk) * 64 + l) * 8);
            #pragma unroll
            for (int i = 0; i < 2; ++i)
                acc[i][j] = __builtin_amdgcn_mfma_f32_16x16x32_bf16(
                    av_[i][kk], bv, acc[i][j], 0, 0, 0);
        }
    }

    #pragma unroll
    for (int j = 0; j < 8; ++j) {
        float bj = bias[j * 16 + lr];
        float s = 0.f;
        #pragma unroll
        for (int i = 0; i < 2; ++i) {
            #pragma unroll
            for (int r = 0; r < 4; ++r) {
                int row = rw0 + i * 16 + lg * 4 + r;
                if (row < N) s += tanhf(acc[i][j][r] + bj);
            }
        }
        s += __shfl_xor(s, 16, 64);
        s += __shfl_xor(s, 32, 64);
        if (lg == 0) sred[w][j * 16 + lr] = s;
    }
    __syncthreads();
    if (tid < 128) {
        float t = sred[0][tid] + sred[1][tid] + sred[2][tid] + sred[3][tid];
        atomicAdd(mc + tid, t);
    }
}

// ---------------- CSR build ----------------
__global__ __launch_bounds__(256) void hist_dst(const int* __restrict__ ei, int* __restrict__ deg)
{
    int e = blockIdx.x * 256 + threadIdx.x;
    if (e < NEDGE) atomicAdd(deg + ei[NEDGE + e], 1);
}

__global__ __launch_bounds__(1024) void scan_block(const int* __restrict__ deg,
    int* __restrict__ offs, int* __restrict__ bsum, int N)
{
    __shared__ int sd[1024];
    int t = threadIdx.x, i = blockIdx.x * 1024 + t;
    int v = (i < N) ? deg[i] : 0;
    sd[t] = v; __syncthreads();
    for (int o = 1; o < 1024; o <<= 1) {
        int x = (t >= o) ? sd[t - o] : 0;
        __syncthreads();
        sd[t] += x;
        __syncthreads();
    }
    if (i < N) offs[i + 1] = sd[t];
    if (t == 1023) bsum[blockIdx.x] = sd[t];
}

__global__ void scan_bsum(const int* __restrict__ bsum, int* __restrict__ boff, int nb)
{
    if (threadIdx.x == 0) {
        int run = 0;
        for (int b = 0; b < nb; ++b) { boff[b] = run; run += bsum[b]; }
    }
}

__global__ __launch_bounds__(1024) void scan_add(int* __restrict__ offs,
    const int* __restrict__ boff, int N)
{
    int i = blockIdx.x * 1024 + threadIdx.x;
    if (i == 0) offs[0] = 0;
    if (i < N) offs[i + 1] += boff[blockIdx.x];
}

__global__ __launch_bounds__(256) void copy_int(const int* __restrict__ src,
    int* __restrict__ dst, int n)
{
    int i = blockIdx.x * 256 + threadIdx.x;
    if (i < n) dst[i] = src[i];
}

__global__ __launch_bounds__(256) void scatter_src(const int* __restrict__ ei,
    int* __restrict__ cursor, int* __restrict__ cols)
{
    int e = blockIdx.x * 256 + threadIdx.x;
    if (e < NEDGE) {
        int d = ei[NEDGE + e];
        int pos = atomicAdd(cursor + d, 1);
        cols[pos] = ei[e];
    }
}

// ---------------- gather aggregation (bf16 z/out) ----------------
__global__ __launch_bounds__(256) void agg_gather(
    const int* __restrict__ offs, const int* __restrict__ cols,
    const float* __restrict__ asrc, const float* __restrict__ adst,
    const ushort* __restrict__ z, ushort* __restrict__ out)
{
    int w = threadIdx.x >> 6;
    int lane = threadIdx.x & 63;
    int d = blockIdx.x * 4 + w;
    if (d >= NNODE) return;
    int h = lane >> 3;
    float ad = adst[d * 8 + h];
    int e0 = offs[d], e1 = offs[d + 1];
    float acc0 = 0.f, acc1 = 0.f, psum = 0.f;
    for (int e = e0; e < e1; ++e) {
        int s = cols[e];
        float a = asrc[s * 8 + h] + ad;
        a = (a >= 0.f) ? a : NEG * a;
        float p = __expf(a);
        unsigned int zp = *reinterpret_cast<const unsigned int*>(z + (size_t)s * 128 + lane * 2);
        acc0 = fmaf(p, b2f(zp & 0xffffu), acc0);
        acc1 = fmaf(p, b2f(zp >> 16), acc1);
        psum += p;
    }
    float inv = 1.f / (psum + 1e-16f);
    float o0 = fmaxf(acc0 * inv, 0.f);
    float o1 = fmaxf(acc1 * inv, 0.f);
    unsigned int packed = (unsigned int)f2b(o0) | ((unsigned int)f2b(o1) << 16);
    *reinterpret_cast<unsigned int*>(out + (size_t)d * 128 + lane * 2) = packed;
}

// softmax over the two semantic scores
__global__ void attn_small(const float* __restrict__ macc,
                           const float* __restrict__ qv, float* __restrict__ attn)
{
    __shared__ float s0[128], s1[128];
    int t = threadIdx.x;
    s0[t] = macc[t] * qv[t];
    s1[t] = macc[128 + t] * qv[t];
    __syncthreads();
    if (t == 0) {
        float a = 0.f, b = 0.f;
        for (int i = 0; i < 128; ++i) { a += s0[i]; b += s1[i]; }
        a *= (1.0f / 100000.0f);
        b *= (1.0f / 100000.0f);
        float m = fmaxf(a, b);
        float ea = expf(a - m), eb = expf(b - m);
        float inv = 1.f / (ea + eb);
        attn[0] = ea * inv;
        attn[1] = eb * inv;
    }
}

// dst = attn[0]*inA + attn[1]*inB, bf16, 8 elems/thread
__global__ __launch_bounds__(256) void combine2b(
    ushort* __restrict__ dst, const ushort* __restrict__ inA,
    const ushort* __restrict__ inB, const float* __restrict__ attn, int n8)
{
    int i = blockIdx.x * 256 + threadIdx.x;
    if (i >= n8) return;
    float a0 = attn[0], a1 = attn[1];
    uint4 A = reinterpret_cast<const uint4*>(inA)[i];
    uint4 B = reinterpret_cast<const uint4*>(inB)[i];
    auto mix = [&](unsigned int a, unsigned int b) -> unsigned int {
        float lo = a0 * b2f(a & 0xffffu) + a1 * b2f(b & 0xffffu);
        float hi = a0 * b2f(a >> 16) + a1 * b2f(b >> 16);
        return (unsigned int)f2b(lo) | ((unsigned int)f2b(hi) << 16);
    };
    uint4 R;
    R.x = mix(A.x, B.x); R.y = mix(A.y, B.y);
    R.z = mix(A.z, B.z); R.w = mix(A.w, B.w);
    reinterpret_cast<uint4*>(dst)[i] = R;
}

// out[N][8] = X_bf16[N][128] @ W[128][8] + bias
__global__ __launch_bounds__(256) void final_gemm_b(
    const ushort* __restrict__ X, const float* __restrict__ W,
    const float* __restrict__ bias, float* __restrict__ out, int N)
{
    __shared__ float Ws[128][8];
    __shared__ __align__(16) float Xs[32][129];
    int tid = threadIdx.x;
    for (int i = tid; i < 1024; i += 256) Ws[i >> 3][i & 7] = W[i];
    int row0 = blockIdx.x * 32;
    for (int i = tid; i < 512; i += 256) {
        int r = i >> 4, q = i & 15;
        int gr = row0 + r;
        uint4 v = make_uint4(0, 0, 0, 0);
        if (gr < N) v = reinterpret_cast<const uint4*>(X + (size_t)gr * 128)[q];
        int c = q * 8;
        Xs[r][c+0] = b2f(v.x & 0xffffu); Xs[r][c+1] = b2f(v.x >> 16);
        Xs[r][c+2] = b2f(v.y & 0xffffu); Xs[r][c+3] = b2f(v.y >> 16);
        Xs[r][c+4] = b2f(v.z & 0xffffu); Xs[r][c+5] = b2f(v.z >> 16);
        Xs[r][c+6] = b2f(v.w & 0xffffu); Xs[r][c+7] = b2f(v.w >> 16);
    }
    __syncthreads();
    int r = tid >> 3, o = tid & 7;
    int gr = row0 + r;
    if (gr < N) {
        float s = bias[o];
        #pragma unroll
        for (int k = 0; k < 128; ++k) s = fmaf(Xs[r][k], Ws[k][o], s);
        out[(size_t)gr * 8 + o] = s;
    }
}

extern "C" void kernel_launch(void* const* d_in, const int* in_sizes, int n_in,
                              void* d_out, int out_size, void* d_ws, size_t ws_size,
                              hipStream_t stream) {
    const float* x_paper  = (const float*)d_in[0];
    const float* x_author = (const float*)d_in[1];
    const float* Wp_p = (const float*)d_in[2];
    const float* bp_p = (const float*)d_in[3];
    const float* Wp_a = (const float*)d_in[4];
    const float* bp_a = (const float*)d_in[5];
    const float* as_ap = (const float*)d_in[6];
    const float* ad_ap = (const float*)d_in[7];
    const float* as_pa = (const float*)d_in[8];
    const float* ad_pa = (const float*)d_in[9];
    const float* as_pp = (const float*)d_in[10];
    const float* ad_pp = (const float*)d_in[11];
    const float* Wk   = (const float*)d_in[12];
    const float* bk   = (const float*)d_in[13];
    const float* qv   = (const float*)d_in[14];
    const float* Wout = (const float*)d_in[15];
    const float* bout = (const float*)d_in[16];
    const int* ei_ap = (const int*)d_in[17];
    const int* ei_pa = (const int*)d_in[18];
    const int* ei_pp = (const int*)d_in[19];

    const size_t NB = (size_t)NNODE * 128;   // 12.8M elems
    ushort* XP = (ushort*)d_ws;
    ushort* XA = XP + NB;
    ushort* Z0 = XA + NB;
    ushort* Z1 = Z0 + NB;
    ushort* Z2 = Z1 + NB;
    ushort* Z3 = Z2 + NB;
    float* fp = (float*)(Z3 + NB);
    float* ap_s = fp; fp += NNODE * 8;
    float* ap_d = fp; fp += NNODE * 8;
    float* pa_s = fp; fp += NNODE * 8;
    float* pa_d = fp; fp += NNODE * 8;
    float* pp_s = fp; fp += NNODE * 8;
    float* pp_d = fp; fp += NNODE * 8;
    float* macc = fp; fp += 256;
    float* attn = fp; fp += 16;
    float* bAv_p0 = fp; fp += 32;
    float* bAv_a0 = fp; fp += 32;
    float* bAv_p1 = fp; fp += 32;
    float* bAv_a1 = fp; fp += 32;
    ushort* up = (ushort*)fp;
    ushort* WtP0 = up; up += 16384;
    ushort* WtA0 = up; up += 16384;
    ushort* WtP1 = up; up += 16384;
    ushort* WtA1 = up; up += 16384;
    ushort* WtK0 = up; up += 16384;
    ushort* WtK1 = up; up += 16384;
    ushort* G_p0 = up; up += 4096;
    ushort* G_a0 = up; up += 4096;
    ushort* G_p1 = up; up += 4096;
    ushort* G_a1 = up; up += 4096;
    int* ip = (int*)(((size_t)up + 15) & ~(size_t)15);
    int* cols_ap = ip; ip += NEDGE;
    int* cols_pa = ip; ip += NEDGE;
    int* cols_pp = ip; ip += NEDGE;
    int* offs_ap = ip; ip += NNODE + 1;
    int* offs_pa = ip; ip += NNODE + 1;
    int* offs_pp = ip; ip += NNODE + 1;
    int* deg     = ip; ip += NNODE;
    int* cursor  = ip; ip += NNODE;
    int* bsum    = ip; ip += 256;
    int* boff    = ip; ip += 256;
    // total ~181 MB

    const dim3 blk(256);
    const int gemmGrid = (NNODE + 127) / 128;     // 782
    const int aggGrid  = (NNODE + 3) / 4;         // 25000
    const int cmbGrid  = (NNODE * 16 + 255) / 256;// 6250
    const int cvtGrid  = (NNODE * 32 + 255) / 256;// 12500
    const int scanNB   = (NNODE + 1023) / 1024;   // 98
    const int wo = 128 * 128, bo = 128, ao = 128;

    // ---- prep: conversions, frag-major weights, fused alpha matrices, CSRs ----
    cvt_x<<<cvtGrid, blk, 0, stream>>>(x_paper,  XP, NNODE * 32);
    cvt_x<<<cvtGrid, blk, 0, stream>>>(x_author, XA, NNODE * 32);
    cvt_wt_fm<<<64, blk, 0, stream>>>(Wp_p,      WtP0);
    cvt_wt_fm<<<64, blk, 0, stream>>>(Wp_a,      WtA0);
    cvt_wt_fm<<<64, blk, 0, stream>>>(Wp_p + wo, WtP1);
    cvt_wt_fm<<<64, blk, 0, stream>>>(Wp_a + wo, WtA1);
    cvt_wt_fm<<<64, blk, 0, stream>>>(Wk,        WtK0);
    cvt_wt_fm<<<64, blk, 0, stream>>>(Wk + wo,   WtK1);
    build_wav<<<16, blk, 0, stream>>>(Wp_p, bp_p, ad_ap, as_pa, as_pp, ad_pp, G_p0, bAv_p0);
    build_wav<<<16, blk, 0, stream>>>(Wp_a, bp_a, as_ap, ad_pa, nullptr, nullptr, G_a0, bAv_a0);
    build_wav<<<16, blk, 0, stream>>>(Wp_p + wo, bp_p + bo, ad_ap + ao, as_pp + ao, ad_pp + ao, nullptr, G_p1, bAv_p1);
    build_wav<<<16, blk, 0, stream>>>(Wp_a + wo, bp_a + bo, as_ap + ao, nullptr, nullptr, nullptr, G_a1, bAv_a1);

    auto build_csr = [&](const int* ei, int* offs, int* cols) {
        hipMemsetAsync(deg, 0, NNODE * 4, stream);
        hist_dst<<<(NEDGE + 255) / 256, blk, 0, stream>>>(ei, deg);
        scan_block<<<scanNB, 1024, 0, stream>>>(deg, offs, bsum, NNODE);
        scan_bsum<<<1, 64, 0, stream>>>(bsum, boff, scanNB);
        scan_add<<<scanNB, 1024, 0, stream>>>(offs, boff, NNODE);
        copy_int<<<(NNODE + 255) / 256, blk, 0, stream>>>(offs, cursor, NNODE);
        scatter_src<<<(NEDGE + 255) / 256, blk, 0, stream>>>(ei, cursor, cols);
    };
    build_csr(ei_ap, offs_ap, cols_ap);
    build_csr(ei_pa, offs_pa, cols_pa);
    build_csr(ei_pp, offs_pp, cols_pp);

    // ---------------- Layer 0 ----------------
    {
        GemmArgs gp{XP, WtP0, G_p0, bp_p, bAv_p0, Z0, ap_d, pa_s, pp_s, pp_d};
        GemmArgs ga{XA, WtA0, G_a0, bp_a, bAv_a0, Z1, ap_s, pa_d, nullptr, nullptr};
        gemm_mfma_dual<<<2 * gemmGrid, blk, 0, stream>>>(gp, ga, gemmGrid, NNODE);
    }

    agg_gather<<<aggGrid, blk, 0, stream>>>(offs_ap, cols_ap, ap_s, ap_d, Z1, Z2); // out_ap
    agg_gather<<<aggGrid, blk, 0, stream>>>(offs_pa, cols_pa, pa_s, pa_d, Z0, Z3); // out_pa = new_xa
    agg_gather<<<aggGrid, blk, 0, stream>>>(offs_pp, cols_pp, pp_s, pp_d, Z0, Z1); // out_pp

    hipMemsetAsync(macc, 0, 256 * 4, stream);
    score_mfma_dual<<<2 * gemmGrid, blk, 0, stream>>>(Z2, Z1, WtK0, bk, macc, gemmGrid, NNODE);
    attn_small<<<1, 128, 0, stream>>>(macc, qv, attn);
    combine2b<<<cmbGrid, blk, 0, stream>>>(Z0, Z2, Z1, attn, NNODE * 16); // new_xp -> Z0

    // ---------------- Layer 1 ----------------  (pa edge type dead here)
    {
        GemmArgs gp{Z0, WtP1, G_p1, bp_p + bo, bAv_p1, Z2, ap_d, pp_s, pp_d, nullptr};
        GemmArgs ga{Z3, WtA1, G_a1, bp_a + bo, bAv_a1, Z1, ap_s, nullptr, nullptr, nullptr};
        gemm_mfma_dual<<<2 * gemmGrid, blk, 0, stream>>>(gp, ga, gemmGrid, NNODE);
    }

    agg_gather<<<aggGrid, blk, 0, stream>>>(offs_ap, cols_ap, ap_s, ap_d, Z1, Z0); // out_ap -> Z0
    agg_gather<<<aggGrid, blk, 0, stream>>>(offs_pp, cols_pp, pp_s, pp_d, Z2, Z3); // out_pp -> Z3

    hipMemsetAsync(macc, 0, 256 * 4, stream);
    score_mfma_dual<<<2 * gemmGrid, blk, 0, stream>>>(Z0, Z3, WtK1, bk + bo, macc, gemmGrid, NNODE);
    attn_small<<<1, 128, 0, stream>>>(macc, qv + bo, attn);
    combine2b<<<cmbGrid, blk, 0, stream>>>(Z1, Z0, Z3, attn, NNODE * 16); // new_xp -> Z1

    final_gemm_b<<<(NNODE + 31) / 32, blk, 0, stream>>>(Z1, Wout, bout, (float*)d_out, NNODE);
}

// Round 7
// 837.323 us; speedup vs baseline: 22.8314x; 1.0306x over previous
//
#include <hip/hip_runtime.h>

#define NHID 128
#define NHEAD 8
#define NNODE 100000
#define NEDGE 500000
#define NEG 0.2f
#define SCORE_GRID 512
#define GEMM_GRID 1024

typedef float4 f4;
typedef __attribute__((ext_vector_type(8))) short bfrag;   // 8 bf16 (4 VGPR)
typedef __attribute__((ext_vector_type(4))) float facc;    // 4 f32 acc

__device__ inline float b2f(unsigned int u) {
    return __uint_as_float(u << 16);
}
__device__ inline unsigned short f2b(float f) {
    unsigned int u = __float_as_uint(f);
    unsigned int r = (u + 0x7FFFu + ((u >> 16) & 1u)) >> 16;
    return (unsigned short)r;
}
__device__ inline float fast_tanh(float x) {
    float e = __expf(2.f * x);
    return 1.f - 2.f / (e + 1.f);
}

// ---------------- prep kernels ----------------
// frag-major W^T: WtT[(((j*4+kk)*64 + l)*8 + e] = W[kk*32+(l>>4)*8+e][j*16+(l&15)]
__global__ __launch_bounds__(256) void cvt_wt_fm(const float* __restrict__ W,
                                                 ushort* __restrict__ WtT)
{
    int i = blockIdx.x * 256 + threadIdx.x;
    if (i >= 16384) return;
    int fi = i >> 3, e = i & 7;
    int jk = fi >> 6, l = fi & 63;
    int j = jk >> 2, kk = jk & 3;
    int lr = l & 15, lg = l >> 4;
    int n = j * 16 + lr;
    int k = kk * 32 + lg * 8 + e;
    WtT[i] = f2b(W[k * 128 + n]);
}

// frag-major G + bias-dot
__global__ __launch_bounds__(256) void build_wav(
    const float* __restrict__ W, const float* __restrict__ b,
    const float* v0, const float* v1, const float* v2, const float* v3,
    ushort* __restrict__ GT, float* __restrict__ bAv)
{
    int i = blockIdx.x * 256 + threadIdx.x;
    if (i >= 4096) return;
    int fi = i >> 3, e = i & 7;
    int jk = fi >> 6, l = fi & 63;
    int jt = jk >> 2, kk = jk & 3;
    int lr = l & 15, lg = l >> 4;
    int c = jt * 16 + lr;
    int m = kk * 32 + lg * 8 + e;
    int vec = c >> 3, h = c & 7;
    const float* vp = (vec == 0) ? v0 : (vec == 1) ? v1 : (vec == 2) ? v2 : v3;
    float s = 0.f;
    if (vp) {
        #pragma unroll
        for (int dd = 0; dd < 16; ++dd)
            s = fmaf(W[m * 128 + h * 16 + dd], vp[h * 16 + dd], s);
    }
    GT[i] = f2b(s);
    if (i < 32) {
        int cc = i;
        int vv = cc >> 3, hh = cc & 7;
        const float* vq = (vv == 0) ? v0 : (vv == 1) ? v1 : (vv == 2) ? v2 : v3;
        float t = 0.f;
        if (vq) {
            #pragma unroll
            for (int dd = 0; dd < 16; ++dd)
                t = fmaf(b[hh * 16 + dd], vq[hh * 16 + dd], t);
        }
        bAv[cc] = t;
    }
}

// ---------------- persistent MFMA GEMM ----------------
// mode 0: A is bf16; mode 1: A is fp32 (converted on load); mode 2: A = a0*A + a1*A2 (both bf16)
struct PArgs {
    const void* A;
    const ushort* A2;
    const ushort* WtT;
    const ushort* GT;
    const float* bias;
    const float* bAv;
    ushort* C;
    float* ao0; float* ao1; float* ao2; float* ao3;
    int mode;
};

__global__ __launch_bounds__(256) void gemm_persist(
    PArgs g0, PArgs g1, const float* __restrict__ attn, int nt, int N)
{
    __shared__ uint4 smem[2560];            // 32KB W + 8KB G
    const int hg = gridDim.x >> 1;
    const int half = (blockIdx.x >= hg) ? 1 : 0;
    const PArgs ga = half ? g1 : g0;
    const int b0 = half ? blockIdx.x - hg : blockIdx.x;

    const int tid = threadIdx.x;
    const int l = tid & 63, w = tid >> 6;
    const int lr = l & 15, lg = l >> 4;

    {
        const uint4* ws = reinterpret_cast<const uint4*>(ga.WtT);
        const uint4* gs = reinterpret_cast<const uint4*>(ga.GT);
        #pragma unroll
        for (int i = 0; i < 8; ++i) smem[tid + i * 256] = ws[tid + i * 256];
        #pragma unroll
        for (int i = 0; i < 2; ++i) smem[2048 + tid + i * 256] = gs[tid + i * 256];
    }
    float a0 = 0.f, a1 = 0.f;
    if (ga.mode == 2) { a0 = attn[0]; a1 = attn[1]; }
    __syncthreads();
    const ushort* WtL = reinterpret_cast<const ushort*>(smem);
    const ushort* GL  = WtL + 16384;

    float bv[8];
    #pragma unroll
    for (int j = 0; j < 8; ++j) bv[j] = ga.bias[j * 16 + lr];
    float bA[2];
    #pragma unroll
    for (int jt = 0; jt < 2; ++jt) bA[jt] = ga.bAv[jt * 16 + lr];

    for (int t = b0; t < nt; t += hg) {
        const int rw0 = t * 128 + w * 32;

        bfrag av_[2][4];
        if (ga.mode == 0) {
            const ushort* Ab = (const ushort*)ga.A;
            #pragma unroll
            for (int i = 0; i < 2; ++i) {
                int r = rw0 + i * 16 + lr; r = (r < N) ? r : (N - 1);
                const ushort* ap = Ab + (size_t)r * 128 + lg * 8;
                #pragma unroll
                for (int kk = 0; kk < 4; ++kk)
                    av_[i][kk] = *reinterpret_cast<const bfrag*>(ap + kk * 32);
            }
        } else if (ga.mode == 1) {
            const float* Af = (const float*)ga.A;
            #pragma unroll
            for (int i = 0; i < 2; ++i) {
                int r = rw0 + i * 16 + lr; r = (r < N) ? r : (N - 1);
                const float* ap = Af + (size_t)r * 128 + lg * 8;
                #pragma unroll
                for (int kk = 0; kk < 4; ++kk) {
                    f4 u = *reinterpret_cast<const f4*>(ap + kk * 32);
                    f4 v = *reinterpret_cast<const f4*>(ap + kk * 32 + 4);
                    bfrag fr;
                    fr[0] = (short)f2b(u.x); fr[1] = (short)f2b(u.y);
                    fr[2] = (short)f2b(u.z); fr[3] = (short)f2b(u.w);
                    fr[4] = (short)f2b(v.x); fr[5] = (short)f2b(v.y);
                    fr[6] = (short)f2b(v.z); fr[7] = (short)f2b(v.w);
                    av_[i][kk] = fr;
                }
            }
        } else {
            const ushort* Aa = (const ushort*)ga.A;
            const ushort* Ab2 = ga.A2;
            #pragma unroll
            for (int i = 0; i < 2; ++i) {
                int r = rw0 + i * 16 + lr; r = (r < N) ? r : (N - 1);
                const ushort* pa = Aa + (size_t)r * 128 + lg * 8;
                const ushort* pb = Ab2 + (size_t)r * 128 + lg * 8;
                #pragma unroll
                for (int kk = 0; kk < 4; ++kk) {
                    uint4 ua = *reinterpret_cast<const uint4*>(pa + kk * 32);
                    uint4 ub = *reinterpret_cast<const uint4*>(pb + kk * 32);
                    unsigned int aa[4] = {ua.x, ua.y, ua.z, ua.w};
                    unsigned int bb[4] = {ub.x, ub.y, ub.z, ub.w};
                    bfrag fr;
                    #pragma unroll
                    for (int q = 0; q < 4; ++q) {
                        float lo = a0 * b2f(aa[q] & 0xffffu) + a1 * b2f(bb[q] & 0xffffu);
                        float hi = a0 * b2f(aa[q] >> 16)     + a1 * b2f(bb[q] >> 16);
                        fr[q * 2]     = (short)f2b(lo);
                        fr[q * 2 + 1] = (short)f2b(hi);
                    }
                    av_[i][kk] = fr;
                }
            }
        }

        facc accC[2][8], accP[2][2];
        #pragma unroll
        for (int i = 0; i < 2; ++i) {
            #pragma unroll
            for (int j = 0; j < 8; ++j) accC[i][j] = (facc){0.f, 0.f, 0.f, 0.f};
            #pragma unroll
            for (int jt = 0; jt < 2; ++jt) accP[i][jt] = (facc){0.f, 0.f, 0.f, 0.f};
        }

        #pragma unroll
        for (int kk = 0; kk < 4; ++kk) {
            #pragma unroll
            for (int j = 0; j < 8; ++j) {
                bfrag bfr = *reinterpret_cast<const bfrag*>(WtL + ((j * 4 + kk) * 64 + l) * 8);
                #pragma unroll
                for (int i = 0; i < 2; ++i)
                    accC[i][j] = __builtin_amdgcn_mfma_f32_16x16x32_bf16(
                        av_[i][kk], bfr, accC[i][j], 0, 0, 0);
            }
            #pragma unroll
            for (int jt = 0; jt < 2; ++jt) {
                bfrag gfr = *reinterpret_cast<const bfrag*>(GL + ((jt * 4 + kk) * 64 + l) * 8);
                #pragma unroll
                for (int i = 0; i < 2; ++i)
                    accP[i][jt] = __builtin_amdgcn_mfma_f32_16x16x32_bf16(
                        av_[i][kk], gfr, accP[i][jt], 0, 0, 0);
            }
        }

        #pragma unroll
        for (int j = 0; j < 8; ++j) {
            #pragma unroll
            for (int i = 0; i < 2; ++i) {
                #pragma unroll
                for (int r = 0; r < 4; ++r) {
                    int row = rw0 + i * 16 + lg * 4 + r;
                    if (row < N)
                        ga.C[(size_t)row * 128 + j * 16 + lr] = f2b(accC[i][j][r] + bv[j]);
                }
            }
        }

        #pragma unroll
        for (int jt = 0; jt < 2; ++jt) {
            int c = jt * 16 + lr;
            int vec = c >> 3, h = c & 7;
            float* ao = (vec == 0) ? ga.ao0 : (vec == 1) ? ga.ao1 : (vec == 2) ? ga.ao2 : ga.ao3;
            if (ao == nullptr) continue;
            #pragma unroll
            for (int i = 0; i < 2; ++i) {
                #pragma unroll
                for (int r = 0; r < 4; ++r) {
                    int row = rw0 + i * 16 + lg * 4 + r;
                    if (row < N) ao[row * 8 + h] = accP[i][jt][r] + bA[jt];
                }
            }
        }
    }
}

// ---------------- persistent MFMA score: partial colsums, no atomics ----------
__global__ __launch_bounds__(256) void score_persist(
    const ushort* __restrict__ A0, const ushort* __restrict__ A1,
    const ushort* __restrict__ WtT, const float* __restrict__ bias,
    float* __restrict__ part, int nt, int N)
{
    __shared__ uint4 smem[2048];            // 32KB W (shared by both halves)
    __shared__ float sred[4][256];
    const int tid = threadIdx.x;
    const int l = tid & 63, w = tid >> 6;
    const int lr = l & 15, lg = l >> 4;

    {
        const uint4* ws = reinterpret_cast<const uint4*>(WtT);
        #pragma unroll
        for (int i = 0; i < 8; ++i) smem[tid + i * 256] = ws[tid + i * 256];
    }
    __syncthreads();
    const ushort* WtL = reinterpret_cast<const ushort*>(smem);

    float bv[8];
    #pragma unroll
    for (int j = 0; j < 8; ++j) bv[j] = bias[j * 16 + lr];

    float cs[2][8];
    #pragma unroll
    for (int h = 0; h < 2; ++h)
        #pragma unroll
        for (int j = 0; j < 8; ++j) cs[h][j] = 0.f;

    const int total = 2 * nt;
    for (int t = blockIdx.x; t < total; t += gridDim.x) {
        const int half = (t >= nt) ? 1 : 0;
        const ushort* A = half ? A1 : A0;
        const int bb = half ? t - nt : t;
        const int rw0 = bb * 128 + w * 32;

        bfrag av_[2][4];
        #pragma unroll
        for (int i = 0; i < 2; ++i) {
            int r = rw0 + i * 16 + lr; r = (r < N) ? r : (N - 1);
            const ushort* ap = A + (size_t)r * 128 + lg * 8;
            #pragma unroll
            for (int kk = 0; kk < 4; ++kk)
                av_[i][kk] = *reinterpret_cast<const bfrag*>(ap + kk * 32);
        }

        facc acc[2][8];
        #pragma unroll
        for (int i = 0; i < 2; ++i)
            #pragma unroll
            for (int j = 0; j < 8; ++j) acc[i][j] = (facc){0.f, 0.f, 0.f, 0.f};

        #pragma unroll
        for (int kk = 0; kk < 4; ++kk) {
            #pragma unroll
            for (int j = 0; j < 8; ++j) {
                bfrag bfr = *reinterpret_cast<const bfrag*>(WtL + ((j * 4 + kk) * 64 + l) * 8);
                #pragma unroll
                for (int i = 0; i < 2; ++i)
                    acc[i][j] = __builtin_amdgcn_mfma_f32_16x16x32_bf16(
                        av_[i][kk], bfr, acc[i][j], 0, 0, 0);
            }
        }

        #pragma unroll
        for (int j = 0; j < 8; ++j) {
            float s = 0.f;
            #pragma unroll
            for (int i = 0; i < 2; ++i) {
                #pragma unroll
                for (int r = 0; r < 4; ++r) {
                    int row = rw0 + i * 16 + lg * 4 + r;
                    if (row < N) s += fast_tanh(acc[i][j][r] + bv[j]);
                }
            }
            cs[half][j] += s;
        }
    }

    #pragma unroll
    for (int h = 0; h < 2; ++h)
        #pragma unroll
        for (int j = 0; j < 8; ++j) {
            float s = cs[h][j];
            s += __shfl_xor(s, 16, 64);
            s += __shfl_xor(s, 32, 64);
            if (lg == 0) sred[w][h * 128 + j * 16 + lr] = s;
        }
    __syncthreads();
    float tot = sred[0][tid] + sred[1][tid] + sred[2][tid] + sred[3][tid];
    part[(size_t)blockIdx.x * 256 + tid] = tot;
}

// reduce partials + semantic softmax
__global__ void attn_reduce(const float* __restrict__ part,
                            const float* __restrict__ qv,
                            float* __restrict__ attn, int nb)
{
    __shared__ float sm[256];
    int t = threadIdx.x;
    float s0 = 0.f, s1 = 0.f, s2 = 0.f, s3 = 0.f;
    for (int b = 0; b < nb; b += 4) {
        s0 += part[(size_t)b * 256 + t];
        s1 += part[(size_t)(b + 1) * 256 + t];
        s2 += part[(size_t)(b + 2) * 256 + t];
        s3 += part[(size_t)(b + 3) * 256 + t];
    }
    sm[t] = (s0 + s1 + s2 + s3) * qv[t & 127];
    __syncthreads();
    if (t == 0) {
        float a = 0.f, b = 0.f;
        for (int i = 0; i < 128; ++i) { a += sm[i]; b += sm[128 + i]; }
        a *= (1.0f / 100000.0f);
        b *= (1.0f / 100000.0f);
        float m = fmaxf(a, b);
        float ea = expf(a - m), eb = expf(b - m);
        float inv = 1.f / (ea + eb);
        attn[0] = ea * inv;
        attn[1] = eb * inv;
    }
}

// ---------------- CSR build ----------------
__global__ __launch_bounds__(256) void hist_dst(const int* __restrict__ ei, int* __restrict__ deg)
{
    int e = blockIdx.x * 256 + threadIdx.x;
    if (e < NEDGE) atomicAdd(deg + ei[NEDGE + e], 1);
}

__global__ __launch_bounds__(1024) void scan_block(const int* __restrict__ deg,
    int* __restrict__ offs, int* __restrict__ bsum, int N)
{
    __shared__ int sd[1024];
    int t = threadIdx.x, i = blockIdx.x * 1024 + t;
    int v = (i < N) ? deg[i] : 0;
    sd[t] = v; __syncthreads();
    for (int o = 1; o < 1024; o <<= 1) {
        int x = (t >= o) ? sd[t - o] : 0;
        __syncthreads();
        sd[t] += x;
        __syncthreads();
    }
    if (i < N) offs[i + 1] = sd[t];
    if (t == 1023) bsum[blockIdx.x] = sd[t];
}

__global__ void scan_bsum(const int* __restrict__ bsum, int* __restrict__ boff, int nb)
{
    if (threadIdx.x == 0) {
        int run = 0;
        for (int b = 0; b < nb; ++b) { boff[b] = run; run += bsum[b]; }
    }
}

__global__ __launch_bounds__(1024) void scan_add(int* __restrict__ offs,
    const int* __restrict__ boff, int N)
{
    int i = blockIdx.x * 1024 + threadIdx.x;
    if (i == 0) offs[0] = 0;
    if (i < N) offs[i + 1] += boff[blockIdx.x];
}

__global__ __launch_bounds__(256) void copy_int(const int* __restrict__ src,
    int* __restrict__ dst, int n)
{
    int i = blockIdx.x * 256 + threadIdx.x;
    if (i < n) dst[i] = src[i];
}

__global__ __launch_bounds__(256) void scatter_src(const int* __restrict__ ei,
    int* __restrict__ cursor, int* __restrict__ cols)
{
    int e = blockIdx.x * 256 + threadIdx.x;
    if (e < NEDGE) {
        int d = ei[NEDGE + e];
        int pos = atomicAdd(cursor + d, 1);
        cols[pos] = ei[e];
    }
}

// ---------------- gather aggregation (bf16 z/out) ----------------
__global__ __launch_bounds__(256) void agg_gather(
    const int* __restrict__ offs, const int* __restrict__ cols,
    const float* __restrict__ asrc, const float* __restrict__ adst,
    const ushort* __restrict__ z, ushort* __restrict__ out)
{
    int w = threadIdx.x >> 6;
    int lane = threadIdx.x & 63;
    int d = blockIdx.x * 4 + w;
    if (d >= NNODE) return;
    int h = lane >> 3;
    float ad = adst[d * 8 + h];
    int e0 = offs[d], e1 = offs[d + 1];
    float acc0 = 0.f, acc1 = 0.f, psum = 0.f;
    for (int e = e0; e < e1; ++e) {
        int s = cols[e];
        float a = asrc[s * 8 + h] + ad;
        a = (a >= 0.f) ? a : NEG * a;
        float p = __expf(a);
        unsigned int zp = *reinterpret_cast<const unsigned int*>(z + (size_t)s * 128 + lane * 2);
        acc0 = fmaf(p, b2f(zp & 0xffffu), acc0);
        acc1 = fmaf(p, b2f(zp >> 16), acc1);
        psum += p;
    }
    float inv = 1.f / (psum + 1e-16f);
    float o0 = fmaxf(acc0 * inv, 0.f);
    float o1 = fmaxf(acc1 * inv, 0.f);
    unsigned int packed = (unsigned int)f2b(o0) | ((unsigned int)f2b(o1) << 16);
    *reinterpret_cast<unsigned int*>(out + (size_t)d * 128 + lane * 2) = packed;
}

// out[N][8] = mix(XA_,XB_,attn) @ W[128][8] + bias
__global__ __launch_bounds__(256) void final_gemm_mix(
    const ushort* __restrict__ XA_, const ushort* __restrict__ XB_,
    const float* __restrict__ attn, const float* __restrict__ W,
    const float* __restrict__ bias, float* __restrict__ out, int N)
{
    __shared__ float Ws[128][8];
    __shared__ __align__(16) float Xs[32][129];
    int tid = threadIdx.x;
    float a0 = attn[0], a1 = attn[1];
    for (int i = tid; i < 1024; i += 256) Ws[i >> 3][i & 7] = W[i];
    int row0 = blockIdx.x * 32;
    for (int i = tid; i < 512; i += 256) {
        int r = i >> 4, q = i & 15;
        int gr = row0 + r;
        uint4 va = make_uint4(0, 0, 0, 0), vb = make_uint4(0, 0, 0, 0);
        if (gr < N) {
            va = reinterpret_cast<const uint4*>(XA_ + (size_t)gr * 128)[q];
            vb = reinterpret_cast<const uint4*>(XB_ + (size_t)gr * 128)[q];
        }
        int c = q * 8;
        unsigned int ua[4] = {va.x, va.y, va.z, va.w};
        unsigned int ub[4] = {vb.x, vb.y, vb.z, vb.w};
        #pragma unroll
        for (int qq = 0; qq < 4; ++qq) {
            Xs[r][c + qq * 2]     = a0 * b2f(ua[qq] & 0xffffu) + a1 * b2f(ub[qq] & 0xffffu);
            Xs[r][c + qq * 2 + 1] = a0 * b2f(ua[qq] >> 16)     + a1 * b2f(ub[qq] >> 16);
        }
    }
    __syncthreads();
    int r = tid >> 3, o = tid & 7;
    int gr = row0 + r;
    if (gr < N) {
        float s = bias[o];
        #pragma unroll
        for (int k = 0; k < 128; ++k) s = fmaf(Xs[r][k], Ws[k][o], s);
        out[(size_t)gr * 8 + o] = s;
    }
}

extern "C" void kernel_launch(void* const* d_in, const int* in_sizes, int n_in,
                              void* d_out, int out_size, void* d_ws, size_t ws_size,
                              hipStream_t stream) {
    const float* x_paper  = (const float*)d_in[0];
    const float* x_author = (const float*)d_in[1];
    const float* Wp_p = (const float*)d_in[2];
    const float* bp_p = (const float*)d_in[3];
    const float* Wp_a = (const float*)d_in[4];
    const float* bp_a = (const float*)d_in[5];
    const float* as_ap = (const float*)d_in[6];
    const float* ad_ap = (const float*)d_in[7];
    const float* as_pa = (const float*)d_in[8];
    const float* ad_pa = (const float*)d_in[9];
    const float* as_pp = (const float*)d_in[10];
    const float* ad_pp = (const float*)d_in[11];
    const float* Wk   = (const float*)d_in[12];
    const float* bk   = (const float*)d_in[13];
    const float* qv   = (const float*)d_in[14];
    const float* Wout = (const float*)d_in[15];
    const float* bout = (const float*)d_in[16];
    const int* ei_ap = (const int*)d_in[17];
    const int* ei_pa = (const int*)d_in[18];
    const int* ei_pp = (const int*)d_in[19];

    const size_t NB = (size_t)NNODE * 128;   // 12.8M elems
    ushort* Z0 = (ushort*)d_ws;
    ushort* Z1 = Z0 + NB;
    ushort* Z2 = Z1 + NB;
    ushort* Z3 = Z2 + NB;
    ushort* P0 = Z3 + NB;    // out_pp layer0
    ushort* P1 = P0 + NB;    // out_pp layer1
    float* fp = (float*)(P1 + NB);
    float* ap_s = fp; fp += NNODE * 8;
    float* ap_d = fp; fp += NNODE * 8;
    float* pa_s = fp; fp += NNODE * 8;
    float* pa_d = fp; fp += NNODE * 8;
    float* pp_s = fp; fp += NNODE * 8;
    float* pp_d = fp; fp += NNODE * 8;
    float* part = fp; fp += (size_t)SCORE_GRID * 256;
    float* attn = fp; fp += 16;
    float* bAv_p0 = fp; fp += 32;
    float* bAv_a0 = fp; fp += 32;
    float* bAv_p1 = fp; fp += 32;
    float* bAv_a1 = fp; fp += 32;
    ushort* up = (ushort*)fp;
    ushort* WtP0 = up; up += 16384;
    ushort* WtA0 = up; up += 16384;
    ushort* WtP1 = up; up += 16384;
    ushort* WtA1 = up; up += 16384;
    ushort* WtK0 = up; up += 16384;
    ushort* WtK1 = up; up += 16384;
    ushort* G_p0 = up; up += 4096;
    ushort* G_a0 = up; up += 4096;
    ushort* G_p1 = up; up += 4096;
    ushort* G_a1 = up; up += 4096;
    int* ip = (int*)(((size_t)up + 15) & ~(size_t)15);
    int* cols_ap = ip; ip += NEDGE;
    int* cols_pa = ip; ip += NEDGE;
    int* cols_pp = ip; ip += NEDGE;
    int* offs_ap = ip; ip += NNODE + 1;
    int* offs_pa = ip; ip += NNODE + 1;
    int* offs_pp = ip; ip += NNODE + 1;
    int* deg     = ip; ip += NNODE;
    int* cursor  = ip; ip += NNODE;
    int* bsum    = ip; ip += 256;
    int* boff    = ip; ip += 256;
    // total ~190 MB

    const dim3 blk(256);
    const int nt = (NNODE + 127) / 128;           // 782 tiles per matrix
    const int aggGrid  = (NNODE + 3) / 4;         // 25000
    const int scanNB   = (NNODE + 1023) / 1024;   // 98
    const int wo = 128 * 128, bo = 128, ao = 128;

    // ---- prep ----
    cvt_wt_fm<<<64, blk, 0, stream>>>(Wp_p,      WtP0);
    cvt_wt_fm<<<64, blk, 0, stream>>>(Wp_a,      WtA0);
    cvt_wt_fm<<<64, blk, 0, stream>>>(Wp_p + wo, WtP1);
    cvt_wt_fm<<<64, blk, 0, stream>>>(Wp_a + wo, WtA1);
    cvt_wt_fm<<<64, blk, 0, stream>>>(Wk,        WtK0);
    cvt_wt_fm<<<64, blk, 0, stream>>>(Wk + wo,   WtK1);
    build_wav<<<16, blk, 0, stream>>>(Wp_p, bp_p, ad_ap, as_pa, as_pp, ad_pp, G_p0, bAv_p0);
    build_wav<<<16, blk, 0, stream>>>(Wp_a, bp_a, as_ap, ad_pa, nullptr, nullptr, G_a0, bAv_a0);
    build_wav<<<16, blk, 0, stream>>>(Wp_p + wo, bp_p + bo, ad_ap + ao, as_pp + ao, ad_pp + ao, nullptr, G_p1, bAv_p1);
    build_wav<<<16, blk, 0, stream>>>(Wp_a + wo, bp_a + bo, as_ap + ao, nullptr, nullptr, nullptr, G_a1, bAv_a1);

    auto build_csr = [&](const int* ei, int* offs, int* cols) {
        hipMemsetAsync(deg, 0, NNODE * 4, stream);
        hist_dst<<<(NEDGE + 255) / 256, blk, 0, stream>>>(ei, deg);
        scan_block<<<scanNB, 1024, 0, stream>>>(deg, offs, bsum, NNODE);
        scan_bsum<<<1, 64, 0, stream>>>(bsum, boff, scanNB);
        scan_add<<<scanNB, 1024, 0, stream>>>(offs, boff, NNODE);
        copy_int<<<(NNODE + 255) / 256, blk, 0, stream>>>(offs, cursor, NNODE);
        scatter_src<<<(NEDGE + 255) / 256, blk, 0, stream>>>(ei, cursor, cols);
    };
    build_csr(ei_ap, offs_ap, cols_ap);
    build_csr(ei_pa, offs_pa, cols_pa);
    build_csr(ei_pp, offs_pp, cols_pp);

    // ---------------- Layer 0 ----------------
    {
        PArgs gp{x_paper,  nullptr, WtP0, G_p0, bp_p, bAv_p0, Z0, ap_d, pa_s, pp_s, pp_d, 1};
        PArgs ga{x_author, nullptr, WtA0, G_a0, bp_a, bAv_a0, Z1, ap_s, pa_d, nullptr, nullptr, 1};
        gemm_persist<<<GEMM_GRID, blk, 0, stream>>>(gp, ga, attn, nt, NNODE);
    }

    agg_gather<<<aggGrid, blk, 0, stream>>>(offs_ap, cols_ap, ap_s, ap_d, Z1, Z2); // out_ap
    agg_gather<<<aggGrid, blk, 0, stream>>>(offs_pa, cols_pa, pa_s, pa_d, Z0, Z3); // out_pa = new_xa
    agg_gather<<<aggGrid, blk, 0, stream>>>(offs_pp, cols_pp, pp_s, pp_d, Z0, P0); // out_pp

    score_persist<<<SCORE_GRID, blk, 0, stream>>>(Z2, P0, WtK0, bk, part, nt, NNODE);
    attn_reduce<<<1, 256, 0, stream>>>(part, qv, attn, SCORE_GRID);

    // ---------------- Layer 1 ----------------  (pa edge type dead here)
    {
        PArgs gp{Z2, P0, WtP1, G_p1, bp_p + bo, bAv_p1, Z0, ap_d, pp_s, pp_d, nullptr, 2}; // A = mix
        PArgs ga{Z3, nullptr, WtA1, G_a1, bp_a + bo, bAv_a1, Z1, ap_s, nullptr, nullptr, nullptr, 0};
        gemm_persist<<<GEMM_GRID, blk, 0, stream>>>(gp, ga, attn, nt, NNODE);
    }

    agg_gather<<<aggGrid, blk, 0, stream>>>(offs_ap, cols_ap, ap_s, ap_d, Z1, Z2); // out_ap -> Z2
    agg_gather<<<aggGrid, blk, 0, stream>>>(offs_pp, cols_pp, pp_s, pp_d, Z0, P1); // out_pp -> P1

    score_persist<<<SCORE_GRID, blk, 0, stream>>>(Z2, P1, WtK1, bk + bo, part, nt, NNODE);
    attn_reduce<<<1, 256, 0, stream>>>(part, qv + bo, attn, SCORE_GRID);

    final_gemm_mix<<<(NNODE + 31) / 32, blk, 0, stream>>>(Z2, P1, attn, Wout, bout, (float*)d_out, NNODE);
}

// Round 8
// 832.185 us; speedup vs baseline: 22.9723x; 1.0062x over previous
//
#include <hip/hip_runtime.h>

#define NHID 128
#define NHEAD 8
#define NNODE 100000
#define NEDGE 500000
#define NEG 0.2f
#define SCORE_GRID 512
#define GEMM_GRID 1024

typedef float4 f4;
typedef __attribute__((ext_vector_type(8))) short bfrag;   // 8 bf16 (4 VGPR)
typedef __attribute__((ext_vector_type(4))) float facc;    // 4 f32 acc

__device__ inline float b2f(unsigned int u) {
    return __uint_as_float(u << 16);
}
__device__ inline unsigned short f2b(float f) {
    unsigned int u = __float_as_uint(f);
    unsigned int r = (u + 0x7FFFu + ((u >> 16) & 1u)) >> 16;
    return (unsigned short)r;
}
__device__ inline float fast_tanh(float x) {
    float e = __expf(2.f * x);
    return 1.f - 2.f / (e + 1.f);
}

// ---------------- prep: 6 weight transposes in one launch ----------------
// frag-major W^T: WtT[(((j*4+kk)*64 + l)*8 + e] = W[kk*32+(l>>4)*8+e][j*16+(l&15)]
__global__ __launch_bounds__(256) void cvt_wt6(
    const float* __restrict__ w0, const float* __restrict__ w1,
    const float* __restrict__ w2, const float* __restrict__ w3,
    const float* __restrict__ w4, const float* __restrict__ w5,
    ushort* __restrict__ o0, ushort* __restrict__ o1,
    ushort* __restrict__ o2, ushort* __restrict__ o3,
    ushort* __restrict__ o4, ushort* __restrict__ o5)
{
    int which = blockIdx.x >> 6;
    int i = (blockIdx.x & 63) * 256 + threadIdx.x;
    const float* W = (which == 0) ? w0 : (which == 1) ? w1 : (which == 2) ? w2
                   : (which == 3) ? w3 : (which == 4) ? w4 : w5;
    ushort* Wt = (which == 0) ? o0 : (which == 1) ? o1 : (which == 2) ? o2
               : (which == 3) ? o3 : (which == 4) ? o4 : o5;
    int fi = i >> 3, e = i & 7;
    int jk = fi >> 6, l = fi & 63;
    int j = jk >> 2, kk = jk & 3;
    int lr = l & 15, lg = l >> 4;
    Wt[i] = f2b(W[(kk * 32 + lg * 8 + e) * 128 + j * 16 + lr]);
}

// ---------------- prep: 4 G-matrices in one launch ----------------
struct WavSet {
    const float* W; const float* b;
    const float* v0; const float* v1; const float* v2; const float* v3;
    ushort* GT; float* bAv;
};

__global__ __launch_bounds__(256) void build_wav4(WavSet s0, WavSet s1, WavSet s2, WavSet s3)
{
    int which = blockIdx.x >> 4;
    const WavSet s = (which == 0) ? s0 : (which == 1) ? s1 : (which == 2) ? s2 : s3;
    int i = (blockIdx.x & 15) * 256 + threadIdx.x;
    int fi = i >> 3, e = i & 7;
    int jk = fi >> 6, l = fi & 63;
    int jt = jk >> 2, kk = jk & 3;
    int lr = l & 15, lg = l >> 4;
    int c = jt * 16 + lr;
    int m = kk * 32 + lg * 8 + e;
    int vec = c >> 3, h = c & 7;
    const float* vp = (vec == 0) ? s.v0 : (vec == 1) ? s.v1 : (vec == 2) ? s.v2 : s.v3;
    float sv = 0.f;
    if (vp) {
        #pragma unroll
        for (int dd = 0; dd < 16; ++dd)
            sv = fmaf(s.W[m * 128 + h * 16 + dd], vp[h * 16 + dd], sv);
    }
    s.GT[i] = f2b(sv);
    if (i < 32) {
        int cc = i, vv = cc >> 3, hh = cc & 7;
        const float* vq = (vv == 0) ? s.v0 : (vv == 1) ? s.v1 : (vv == 2) ? s.v2 : s.v3;
        float t = 0.f;
        if (vq) {
            #pragma unroll
            for (int dd = 0; dd < 16; ++dd)
                t = fmaf(s.b[hh * 16 + dd], vq[hh * 16 + dd], t);
        }
        s.bAv[cc] = t;
    }
}

// ---------------- persistent MFMA GEMM (16-row waves, 64-row tiles) --------
// mode 0: A bf16; mode 1: A fp32; mode 2: A = a0*A + a1*A2 (both bf16)
struct PArgs {
    const void* A;
    const ushort* A2;
    const ushort* WtT;
    const ushort* GT;
    const float* bias;
    const float* bAv;
    ushort* C;
    float* ao0; float* ao1; float* ao2; float* ao3;
    int mode;
};

__global__ __launch_bounds__(256, 4) void gemm_persist(
    PArgs g0, PArgs g1, const float* __restrict__ attn, int nt, int N)
{
    __shared__ uint4 smem[2560];            // 32KB W + 8KB G
    const int hg = gridDim.x >> 1;
    const int half = (blockIdx.x >= hg) ? 1 : 0;
    const PArgs ga = half ? g1 : g0;
    const int b0 = half ? blockIdx.x - hg : blockIdx.x;

    const int tid = threadIdx.x;
    const int l = tid & 63, w = tid >> 6;
    const int lr = l & 15, lg = l >> 4;

    {
        const uint4* ws = reinterpret_cast<const uint4*>(ga.WtT);
        const uint4* gs = reinterpret_cast<const uint4*>(ga.GT);
        #pragma unroll
        for (int i = 0; i < 8; ++i) smem[tid + i * 256] = ws[tid + i * 256];
        #pragma unroll
        for (int i = 0; i < 2; ++i) smem[2048 + tid + i * 256] = gs[tid + i * 256];
    }
    float a0 = 0.f, a1 = 0.f;
    if (ga.mode == 2) { a0 = attn[0]; a1 = attn[1]; }
    __syncthreads();
    const ushort* WtL = reinterpret_cast<const ushort*>(smem);
    const ushort* GL  = WtL + 16384;

    float bv[8];
    #pragma unroll
    for (int j = 0; j < 8; ++j) bv[j] = ga.bias[j * 16 + lr];
    float bA[2];
    #pragma unroll
    for (int jt = 0; jt < 2; ++jt) bA[jt] = ga.bAv[jt * 16 + lr];

    for (int t = b0; t < nt; t += hg) {
        const int rw0 = t * 64 + w * 16;
        int r = rw0 + lr; r = (r < N) ? r : (N - 1);

        bfrag av_[4];
        if (ga.mode == 0) {
            const ushort* ap = (const ushort*)ga.A + (size_t)r * 128 + lg * 8;
            #pragma unroll
            for (int kk = 0; kk < 4; ++kk)
                av_[kk] = *reinterpret_cast<const bfrag*>(ap + kk * 32);
        } else if (ga.mode == 1) {
            const float* ap = (const float*)ga.A + (size_t)r * 128 + lg * 8;
            #pragma unroll
            for (int kk = 0; kk < 4; ++kk) {
                f4 u = *reinterpret_cast<const f4*>(ap + kk * 32);
                f4 v = *reinterpret_cast<const f4*>(ap + kk * 32 + 4);
                bfrag fr;
                fr[0] = (short)f2b(u.x); fr[1] = (short)f2b(u.y);
                fr[2] = (short)f2b(u.z); fr[3] = (short)f2b(u.w);
                fr[4] = (short)f2b(v.x); fr[5] = (short)f2b(v.y);
                fr[6] = (short)f2b(v.z); fr[7] = (short)f2b(v.w);
                av_[kk] = fr;
            }
        } else {
            const ushort* pa = (const ushort*)ga.A + (size_t)r * 128 + lg * 8;
            const ushort* pb = ga.A2 + (size_t)r * 128 + lg * 8;
            #pragma unroll
            for (int kk = 0; kk < 4; ++kk) {
                uint4 ua = *reinterpret_cast<const uint4*>(pa + kk * 32);
                uint4 ub = *reinterpret_cast<const uint4*>(pb + kk * 32);
                unsigned int aa[4] = {ua.x, ua.y, ua.z, ua.w};
                unsigned int bb[4] = {ub.x, ub.y, ub.z, ub.w};
                bfrag fr;
                #pragma unroll
                for (int q = 0; q < 4; ++q) {
                    float lo = a0 * b2f(aa[q] & 0xffffu) + a1 * b2f(bb[q] & 0xffffu);
                    float hi = a0 * b2f(aa[q] >> 16)     + a1 * b2f(bb[q] >> 16);
                    fr[q * 2]     = (short)f2b(lo);
                    fr[q * 2 + 1] = (short)f2b(hi);
                }
                av_[kk] = fr;
            }
        }

        facc accC[8], accP[2];
        #pragma unroll
        for (int j = 0; j < 8; ++j) accC[j] = (facc){0.f, 0.f, 0.f, 0.f};
        #pragma unroll
        for (int jt = 0; jt < 2; ++jt) accP[jt] = (facc){0.f, 0.f, 0.f, 0.f};

        #pragma unroll
        for (int kk = 0; kk < 4; ++kk) {
            #pragma unroll
            for (int j = 0; j < 8; ++j) {
                bfrag bfr = *reinterpret_cast<const bfrag*>(WtL + ((j * 4 + kk) * 64 + l) * 8);
                accC[j] = __builtin_amdgcn_mfma_f32_16x16x32_bf16(av_[kk], bfr, accC[j], 0, 0, 0);
            }
            #pragma unroll
            for (int jt = 0; jt < 2; ++jt) {
                bfrag gfr = *reinterpret_cast<const bfrag*>(GL + ((jt * 4 + kk) * 64 + l) * 8);
                accP[jt] = __builtin_amdgcn_mfma_f32_16x16x32_bf16(av_[kk], gfr, accP[jt], 0, 0, 0);
            }
        }

        #pragma unroll
        for (int j = 0; j < 8; ++j) {
            #pragma unroll
            for (int rr = 0; rr < 4; ++rr) {
                int row = rw0 + lg * 4 + rr;
                if (row < N)
                    ga.C[(size_t)row * 128 + j * 16 + lr] = f2b(accC[j][rr] + bv[j]);
            }
        }

        #pragma unroll
        for (int jt = 0; jt < 2; ++jt) {
            int c = jt * 16 + lr;
            int vec = c >> 3, h = c & 7;
            float* ao = (vec == 0) ? ga.ao0 : (vec == 1) ? ga.ao1 : (vec == 2) ? ga.ao2 : ga.ao3;
            if (ao == nullptr) continue;
            #pragma unroll
            for (int rr = 0; rr < 4; ++rr) {
                int row = rw0 + lg * 4 + rr;
                if (row < N) ao[row * 8 + h] = accP[jt][rr] + bA[jt];
            }
        }
    }
}

// ---------------- persistent MFMA score (partial colsums, no atomics) ------
__global__ __launch_bounds__(256) void score_persist(
    const ushort* __restrict__ A0, const ushort* __restrict__ A1,
    const ushort* __restrict__ WtT, const float* __restrict__ bias,
    float* __restrict__ part, int nt, int N)
{
    __shared__ uint4 smem[2048];            // 32KB W
    __shared__ float sred[4][256];
    const int tid = threadIdx.x;
    const int l = tid & 63, w = tid >> 6;
    const int lr = l & 15, lg = l >> 4;

    {
        const uint4* ws = reinterpret_cast<const uint4*>(WtT);
        #pragma unroll
        for (int i = 0; i < 8; ++i) smem[tid + i * 256] = ws[tid + i * 256];
    }
    __syncthreads();
    const ushort* WtL = reinterpret_cast<const ushort*>(smem);

    float bv[8];
    #pragma unroll
    for (int j = 0; j < 8; ++j) bv[j] = bias[j * 16 + lr];

    float cs[2][8];
    #pragma unroll
    for (int h = 0; h < 2; ++h)
        #pragma unroll
        for (int j = 0; j < 8; ++j) cs[h][j] = 0.f;

    const int total = 2 * nt;
    for (int t = blockIdx.x; t < total; t += gridDim.x) {
        const int half = (t >= nt) ? 1 : 0;
        const ushort* A = half ? A1 : A0;
        const int bb = half ? t - nt : t;
        const int rw0 = bb * 128 + w * 32;

        bfrag av_[2][4];
        #pragma unroll
        for (int i = 0; i < 2; ++i) {
            int r = rw0 + i * 16 + lr; r = (r < N) ? r : (N - 1);
            const ushort* ap = A + (size_t)r * 128 + lg * 8;
            #pragma unroll
            for (int kk = 0; kk < 4; ++kk)
                av_[i][kk] = *reinterpret_cast<const bfrag*>(ap + kk * 32);
        }

        facc acc[2][8];
        #pragma unroll
        for (int i = 0; i < 2; ++i)
            #pragma unroll
            for (int j = 0; j < 8; ++j) acc[i][j] = (facc){0.f, 0.f, 0.f, 0.f};

        #pragma unroll
        for (int kk = 0; kk < 4; ++kk) {
            #pragma unroll
            for (int j = 0; j < 8; ++j) {
                bfrag bfr = *reinterpret_cast<const bfrag*>(WtL + ((j * 4 + kk) * 64 + l) * 8);
                #pragma unroll
                for (int i = 0; i < 2; ++i)
                    acc[i][j] = __builtin_amdgcn_mfma_f32_16x16x32_bf16(
                        av_[i][kk], bfr, acc[i][j], 0, 0, 0);
            }
        }

        #pragma unroll
        for (int j = 0; j < 8; ++j) {
            float s = 0.f;
            #pragma unroll
            for (int i = 0; i < 2; ++i) {
                #pragma unroll
                for (int r = 0; r < 4; ++r) {
                    int row = rw0 + i * 16 + lg * 4 + r;
                    if (row < N) s += fast_tanh(acc[i][j][r] + bv[j]);
                }
            }
            cs[half][j] += s;
        }
    }

    #pragma unroll
    for (int h = 0; h < 2; ++h)
        #pragma unroll
        for (int j = 0; j < 8; ++j) {
            float s = cs[h][j];
            s += __shfl_xor(s, 16, 64);
            s += __shfl_xor(s, 32, 64);
            if (lg == 0) sred[w][h * 128 + j * 16 + lr] = s;
        }
    __syncthreads();
    float tot = sred[0][tid] + sred[1][tid] + sred[2][tid] + sred[3][tid];
    part[(size_t)blockIdx.x * 256 + tid] = tot;
}

// reduce partials + semantic softmax
__global__ void attn_reduce(const float* __restrict__ part,
                            const float* __restrict__ qv,
                            float* __restrict__ attn, int nb)
{
    __shared__ float sm[256];
    int t = threadIdx.x;
    float s0 = 0.f, s1 = 0.f, s2 = 0.f, s3 = 0.f;
    for (int b = 0; b < nb; b += 4) {
        s0 += part[(size_t)b * 256 + t];
        s1 += part[(size_t)(b + 1) * 256 + t];
        s2 += part[(size_t)(b + 2) * 256 + t];
        s3 += part[(size_t)(b + 3) * 256 + t];
    }
    sm[t] = (s0 + s1 + s2 + s3) * qv[t & 127];
    __syncthreads();
    if (t == 0) {
        float a = 0.f, b = 0.f;
        for (int i = 0; i < 128; ++i) { a += sm[i]; b += sm[128 + i]; }
        a *= (1.0f / 100000.0f);
        b *= (1.0f / 100000.0f);
        float m = fmaxf(a, b);
        float ea = expf(a - m), eb = expf(b - m);
        float inv = 1.f / (ea + eb);
        attn[0] = ea * inv;
        attn[1] = eb * inv;
    }
}

// ---------------- CSR build (3 edge types per launch) ----------------
#define EB ((NEDGE + 255) / 256)
#define SB ((NNODE + 1023) / 1024)

__global__ __launch_bounds__(256) void hist3(
    const int* __restrict__ e0, const int* __restrict__ e1, const int* __restrict__ e2,
    int* __restrict__ deg3)
{
    int ty = blockIdx.x / EB, bb = blockIdx.x % EB;
    const int* ei = (ty == 0) ? e0 : (ty == 1) ? e1 : e2;
    int e = bb * 256 + threadIdx.x;
    if (e < NEDGE) atomicAdd(deg3 + ty * NNODE + ei[NEDGE + e], 1);
}

__global__ __launch_bounds__(1024) void scan_block3(
    const int* __restrict__ deg3, int* __restrict__ offs3, int* __restrict__ bsum3)
{
    __shared__ int sd[1024];
    int ty = blockIdx.x / SB, bb = blockIdx.x % SB;
    const int* deg = deg3 + ty * NNODE;
    int* offs = offs3 + ty * (NNODE + 1);
    int t = threadIdx.x, i = bb * 1024 + t;
    int v = (i < NNODE) ? deg[i] : 0;
    sd[t] = v; __syncthreads();
    for (int o = 1; o < 1024; o <<= 1) {
        int x = (t >= o) ? sd[t - o] : 0;
        __syncthreads();
        sd[t] += x;
        __syncthreads();
    }
    if (i < NNODE) offs[i + 1] = sd[t];
    if (t == 1023) bsum3[ty * 128 + bb] = sd[t];
}

__global__ void scan_bsum3(const int* __restrict__ bsum3, int* __restrict__ boff3)
{
    int t = threadIdx.x;
    if (t < 3) {
        int run = 0;
        for (int b = 0; b < SB; ++b) { boff3[t * 128 + b] = run; run += bsum3[t * 128 + b]; }
    }
}

__global__ __launch_bounds__(1024) void scan_add3(
    int* __restrict__ offs3, const int* __restrict__ boff3, int* __restrict__ cur3)
{
    int ty = blockIdx.x / SB, bb = blockIdx.x % SB;
    int* offs = offs3 + ty * (NNODE + 1);
    int* cur = cur3 + ty * NNODE;
    int i = bb * 1024 + threadIdx.x;
    if (i == 0) { offs[0] = 0; cur[0] = 0; }
    if (i < NNODE) {
        int v = offs[i + 1] + boff3[ty * 128 + bb];
        offs[i + 1] = v;
        if (i + 1 < NNODE) cur[i + 1] = v;
    }
}

__global__ __launch_bounds__(256) void scatter3(
    const int* __restrict__ e0, const int* __restrict__ e1, const int* __restrict__ e2,
    int* __restrict__ cur3, int* __restrict__ cols3)
{
    int ty = blockIdx.x / EB, bb = blockIdx.x % EB;
    const int* ei = (ty == 0) ? e0 : (ty == 1) ? e1 : e2;
    int e = bb * 256 + threadIdx.x;
    if (e < NEDGE) {
        int d = ei[NEDGE + e];
        int pos = atomicAdd(cur3 + ty * NNODE + d, 1);
        cols3[ty * NEDGE + pos] = ei[e];
    }
}

// ---------------- gather aggregation (bf16, 4-wide edge batching) ----------
__global__ __launch_bounds__(256) void agg_gather(
    const int* __restrict__ offs, const int* __restrict__ cols,
    const float* __restrict__ asrc, const float* __restrict__ adst,
    const ushort* __restrict__ z, ushort* __restrict__ out)
{
    int w = threadIdx.x >> 6;
    int lane = threadIdx.x & 63;
    int d = blockIdx.x * 4 + w;
    if (d >= NNODE) return;
    int h = lane >> 3;
    float ad = adst[d * 8 + h];
    int e0 = offs[d], e1 = offs[d + 1];
    float acc0 = 0.f, acc1 = 0.f, psum = 0.f;
    int e = e0;
    for (; e + 4 <= e1; e += 4) {
        int s0 = cols[e], s1 = cols[e + 1], s2 = cols[e + 2], s3 = cols[e + 3];
        float x0 = asrc[s0 * 8 + h], x1 = asrc[s1 * 8 + h];
        float x2 = asrc[s2 * 8 + h], x3 = asrc[s3 * 8 + h];
        unsigned int q0 = *reinterpret_cast<const unsigned int*>(z + (size_t)s0 * 128 + lane * 2);
        unsigned int q1 = *reinterpret_cast<const unsigned int*>(z + (size_t)s1 * 128 + lane * 2);
        unsigned int q2 = *reinterpret_cast<const unsigned int*>(z + (size_t)s2 * 128 + lane * 2);
        unsigned int q3 = *reinterpret_cast<const unsigned int*>(z + (size_t)s3 * 128 + lane * 2);
        float a;
        a = x0 + ad; a = (a >= 0.f) ? a : NEG * a; float p0 = __expf(a);
        a = x1 + ad; a = (a >= 0.f) ? a : NEG * a; float p1 = __expf(a);
        a = x2 + ad; a = (a >= 0.f) ? a : NEG * a; float p2 = __expf(a);
        a = x3 + ad; a = (a >= 0.f) ? a : NEG * a; float p3 = __expf(a);
        acc0 = fmaf(p0, b2f(q0 & 0xffffu), acc0); acc1 = fmaf(p0, b2f(q0 >> 16), acc1);
        acc0 = fmaf(p1, b2f(q1 & 0xffffu), acc0); acc1 = fmaf(p1, b2f(q1 >> 16), acc1);
        acc0 = fmaf(p2, b2f(q2 & 0xffffu), acc0); acc1 = fmaf(p2, b2f(q2 >> 16), acc1);
        acc0 = fmaf(p3, b2f(q3 & 0xffffu), acc0); acc1 = fmaf(p3, b2f(q3 >> 16), acc1);
        psum += p0 + p1 + p2 + p3;
    }
    for (; e < e1; ++e) {
        int s = cols[e];
        float a = asrc[s * 8 + h] + ad;
        a = (a >= 0.f) ? a : NEG * a;
        float p = __expf(a);
        unsigned int zp = *reinterpret_cast<const unsigned int*>(z + (size_t)s * 128 + lane * 2);
        acc0 = fmaf(p, b2f(zp & 0xffffu), acc0);
        acc1 = fmaf(p, b2f(zp >> 16), acc1);
        psum += p;
    }
    float inv = 1.f / (psum + 1e-16f);
    float o0 = fmaxf(acc0 * inv, 0.f);
    float o1 = fmaxf(acc1 * inv, 0.f);
    unsigned int packed = (unsigned int)f2b(o0) | ((unsigned int)f2b(o1) << 16);
    *reinterpret_cast<unsigned int*>(out + (size_t)d * 128 + lane * 2) = packed;
}

// out[N][8] = mix(XA_,XB_,attn) @ W[128][8] + bias
__global__ __launch_bounds__(256) void final_gemm_mix(
    const ushort* __restrict__ XA_, const ushort* __restrict__ XB_,
    const float* __restrict__ attn, const float* __restrict__ W,
    const float* __restrict__ bias, float* __restrict__ out, int N)
{
    __shared__ float Ws[128][8];
    __shared__ __align__(16) float Xs[32][129];
    int tid = threadIdx.x;
    float a0 = attn[0], a1 = attn[1];
    for (int i = tid; i < 1024; i += 256) Ws[i >> 3][i & 7] = W[i];
    int row0 = blockIdx.x * 32;
    for (int i = tid; i < 512; i += 256) {
        int r = i >> 4, q = i & 15;
        int gr = row0 + r;
        uint4 va = make_uint4(0, 0, 0, 0), vb = make_uint4(0, 0, 0, 0);
        if (gr < N) {
            va = reinterpret_cast<const uint4*>(XA_ + (size_t)gr * 128)[q];
            vb = reinterpret_cast<const uint4*>(XB_ + (size_t)gr * 128)[q];
        }
        int c = q * 8;
        unsigned int ua[4] = {va.x, va.y, va.z, va.w};
        unsigned int ub[4] = {vb.x, vb.y, vb.z, vb.w};
        #pragma unroll
        for (int qq = 0; qq < 4; ++qq) {
            Xs[r][c + qq * 2]     = a0 * b2f(ua[qq] & 0xffffu) + a1 * b2f(ub[qq] & 0xffffu);
            Xs[r][c + qq * 2 + 1] = a0 * b2f(ua[qq] >> 16)     + a1 * b2f(ub[qq] >> 16);
        }
    }
    __syncthreads();
    int r = tid >> 3, o = tid & 7;
    int gr = row0 + r;
    if (gr < N) {
        float s = bias[o];
        #pragma unroll
        for (int k = 0; k < 128; ++k) s = fmaf(Xs[r][k], Ws[k][o], s);
        out[(size_t)gr * 8 + o] = s;
    }
}

extern "C" void kernel_launch(void* const* d_in, const int* in_sizes, int n_in,
                              void* d_out, int out_size, void* d_ws, size_t ws_size,
                              hipStream_t stream) {
    const float* x_paper  = (const float*)d_in[0];
    const float* x_author = (const float*)d_in[1];
    const float* Wp_p = (const float*)d_in[2];
    const float* bp_p = (const float*)d_in[3];
    const float* Wp_a = (const float*)d_in[4];
    const float* bp_a = (const float*)d_in[5];
    const float* as_ap = (const float*)d_in[6];
    const float* ad_ap = (const float*)d_in[7];
    const float* as_pa = (const float*)d_in[8];
    const float* ad_pa = (const float*)d_in[9];
    const float* as_pp = (const float*)d_in[10];
    const float* ad_pp = (const float*)d_in[11];
    const float* Wk   = (const float*)d_in[12];
    const float* bk   = (const float*)d_in[13];
    const float* qv   = (const float*)d_in[14];
    const float* Wout = (const float*)d_in[15];
    const float* bout = (const float*)d_in[16];
    const int* ei_ap = (const int*)d_in[17];
    const int* ei_pa = (const int*)d_in[18];
    const int* ei_pp = (const int*)d_in[19];

    const size_t NB = (size_t)NNODE * 128;   // 12.8M elems
    ushort* Z0 = (ushort*)d_ws;
    ushort* Z1 = Z0 + NB;
    ushort* Z2 = Z1 + NB;
    ushort* Z3 = Z2 + NB;
    ushort* P0 = Z3 + NB;
    ushort* P1 = P0 + NB;
    float* fp = (float*)(P1 + NB);
    float* ap_s = fp; fp += NNODE * 8;
    float* ap_d = fp; fp += NNODE * 8;
    float* pa_s = fp; fp += NNODE * 8;
    float* pa_d = fp; fp += NNODE * 8;
    float* pp_s = fp; fp += NNODE * 8;
    float* pp_d = fp; fp += NNODE * 8;
    float* part = fp; fp += (size_t)SCORE_GRID * 256;
    float* attn = fp; fp += 16;
    float* bAv_p0 = fp; fp += 32;
    float* bAv_a0 = fp; fp += 32;
    float* bAv_p1 = fp; fp += 32;
    float* bAv_a1 = fp; fp += 32;
    ushort* up = (ushort*)fp;
    ushort* WtP0 = up; up += 16384;
    ushort* WtA0 = up; up += 16384;
    ushort* WtP1 = up; up += 16384;
    ushort* WtA1 = up; up += 16384;
    ushort* WtK0 = up; up += 16384;
    ushort* WtK1 = up; up += 16384;
    ushort* G_p0 = up; up += 4096;
    ushort* G_a0 = up; up += 4096;
    ushort* G_p1 = up; up += 4096;
    ushort* G_a1 = up; up += 4096;
    int* ip = (int*)(((size_t)up + 15) & ~(size_t)15);
    int* cols3 = ip; ip += 3 * NEDGE;
    int* offs3 = ip; ip += 3 * (NNODE + 1);
    int* deg3  = ip; ip += 3 * NNODE;
    int* cur3  = ip; ip += 3 * NNODE;
    int* bsum3 = ip; ip += 3 * 128;
    int* boff3 = ip; ip += 3 * 128;

    const int* cols_ap = cols3;
    const int* cols_pa = cols3 + NEDGE;
    const int* cols_pp = cols3 + 2 * NEDGE;
    const int* offs_ap = offs3;
    const int* offs_pa = offs3 + (NNODE + 1);
    const int* offs_pp = offs3 + 2 * (NNODE + 1);

    const dim3 blk(256);
    const int nt64  = (NNODE + 63) / 64;          // 1563 gemm tiles
    const int nt128 = (NNODE + 127) / 128;        // 782 score tiles
    const int aggGrid = (NNODE + 3) / 4;          // 25000
    const int wo = 128 * 128, bo = 128, ao = 128;

    // ---- prep ----
    cvt_wt6<<<384, blk, 0, stream>>>(Wp_p, Wp_a, Wp_p + wo, Wp_a + wo, Wk, Wk + wo,
                                     WtP0, WtA0, WtP1, WtA1, WtK0, WtK1);
    {
        WavSet s0{Wp_p, bp_p, ad_ap, as_pa, as_pp, ad_pp, G_p0, bAv_p0};
        WavSet s1{Wp_a, bp_a, as_ap, ad_pa, nullptr, nullptr, G_a0, bAv_a0};
        WavSet s2{Wp_p + wo, bp_p + bo, ad_ap + ao, as_pp + ao, ad_pp + ao, nullptr, G_p1, bAv_p1};
        WavSet s3{Wp_a + wo, bp_a + bo, as_ap + ao, nullptr, nullptr, nullptr, G_a1, bAv_a1};
        build_wav4<<<64, blk, 0, stream>>>(s0, s1, s2, s3);
    }

    hipMemsetAsync(deg3, 0, 3 * NNODE * 4, stream);
    hist3<<<3 * EB, blk, 0, stream>>>(ei_ap, ei_pa, ei_pp, deg3);
    scan_block3<<<3 * SB, 1024, 0, stream>>>(deg3, offs3, bsum3);
    scan_bsum3<<<1, 64, 0, stream>>>(bsum3, boff3);
    scan_add3<<<3 * SB, 1024, 0, stream>>>(offs3, boff3, cur3);
    scatter3<<<3 * EB, blk, 0, stream>>>(ei_ap, ei_pa, ei_pp, cur3, cols3);

    // ---------------- Layer 0 ----------------
    {
        PArgs gp{x_paper,  nullptr, WtP0, G_p0, bp_p, bAv_p0, Z0, ap_d, pa_s, pp_s, pp_d, 1};
        PArgs ga{x_author, nullptr, WtA0, G_a0, bp_a, bAv_a0, Z1, ap_s, pa_d, nullptr, nullptr, 1};
        gemm_persist<<<GEMM_GRID, blk, 0, stream>>>(gp, ga, attn, nt64, NNODE);
    }

    agg_gather<<<aggGrid, blk, 0, stream>>>(offs_ap, cols_ap, ap_s, ap_d, Z1, Z2); // out_ap
    agg_gather<<<aggGrid, blk, 0, stream>>>(offs_pa, cols_pa, pa_s, pa_d, Z0, Z3); // out_pa = new_xa
    agg_gather<<<aggGrid, blk, 0, stream>>>(offs_pp, cols_pp, pp_s, pp_d, Z0, P0); // out_pp

    score_persist<<<SCORE_GRID, blk, 0, stream>>>(Z2, P0, WtK0, bk, part, nt128, NNODE);
    attn_reduce<<<1, 256, 0, stream>>>(part, qv, attn, SCORE_GRID);

    // ---------------- Layer 1 ----------------  (pa edge type dead here)
    {
        PArgs gp{Z2, P0, WtP1, G_p1, bp_p + bo, bAv_p1, Z0, ap_d, pp_s, pp_d, nullptr, 2}; // A = mix
        PArgs ga{Z3, nullptr, WtA1, G_a1, bp_a + bo, bAv_a1, Z1, ap_s, nullptr, nullptr, nullptr, 0};
        gemm_persist<<<GEMM_GRID, blk, 0, stream>>>(gp, ga, attn, nt64, NNODE);
    }

    agg_gather<<<aggGrid, blk, 0, stream>>>(offs_ap, cols_ap, ap_s, ap_d, Z1, Z2); // out_ap -> Z2
    agg_gather<<<aggGrid, blk, 0, stream>>>(offs_pp, cols_pp, pp_s, pp_d, Z0, P1); // out_pp -> P1

    score_persist<<<SCORE_GRID, blk, 0, stream>>>(Z2, P1, WtK1, bk + bo, part, nt128, NNODE);
    attn_reduce<<<1, 256, 0, stream>>>(part, qv + bo, attn, SCORE_GRID);

    final_gemm_mix<<<(NNODE + 31) / 32, blk, 0, stream>>>(Z2, P1, attn, Wout, bout, (float*)d_out, NNODE);
}